// Round 8
// baseline (411.911 us; speedup 1.0000x reference)
//
#include <hip/hip_runtime.h>

typedef unsigned short u16;
typedef short s16x8 __attribute__((ext_vector_type(8)));
typedef _Float16 h16x8 __attribute__((ext_vector_type(8)));
typedef float f32x4 __attribute__((ext_vector_type(4)));
typedef u16 u16x4 __attribute__((ext_vector_type(4)));

#define DEV static __device__ __forceinline__

// ---------- f16 limb helpers (RTNE via v_cvt_f16_f32) ----------
DEV u16 f2h(float x){ union { _Float16 h; u16 u; } v; v.h = (_Float16)x; return v.u; }
DEV float h2f(u16 u){ union { u16 u; _Float16 h; } v; v.u = u; return (float)v.h; }
DEV void split_h(float x, u16& h, u16& l){
    h = f2h(x);
    l = f2h(x - h2f(h));
}
DEV h16x8 H8(s16x8 v){ union { s16x8 s; h16x8 h; } u; u.s = v; return u.h; }
DEV f32x4 mfma16(s16x8 a, s16x8 b, f32x4 c){
    return __builtin_amdgcn_mfma_f32_16x16x32_f16(H8(a), H8(b), c, 0, 0, 0);
}

// ---------- t-layout chunk swizzle (bits 3-5 of m XOR row&7) ----------
DEV int swz(int r, int m){ return (m & ~0x38) | ((((m >> 3) ^ r) & 7) << 3); }

// global -> LDS direct (16B per lane)
DEV void gll16(const u16* g, u16* l){
    __builtin_amdgcn_global_load_lds((const __attribute__((address_space(1))) void*)g,
                                     (__attribute__((address_space(3))) void*)l, 16, 0, 0);
}

// =====================================================================
// K_prep (merged): blocks 0..2047 = supports softmax rows; rest = prep.
// =====================================================================
__global__ __launch_bounds__(256) void k_prep(const float* __restrict__ E,
    const float* __restrict__ gwp, const float* __restrict__ gbp,
    const float* __restrict__ uwp, const float* __restrict__ ubp,
    const float* __restrict__ x,   const float* __restrict__ state,
    const float* __restrict__ lw,
    u16* __restrict__ wg, u16* __restrict__ wu,
    float* __restrict__ bg, float* __restrict__ bu,
    u16* __restrict__ xt, u16* __restrict__ lwt,
    u16* __restrict__ Sh, u16* __restrict__ Sl)
{
    __shared__ float red[8];
    const int tid = threadIdx.x;
    if (blockIdx.x < 2048){
        const int n = blockIdx.x;
        const int w = tid >> 6, lane = tid & 63;
        float en[10];
        #pragma unroll
        for (int d = 0; d < 10; d++) en[d] = E[n*10 + d];
        float v[8];
        #pragma unroll
        for (int i = 0; i < 8; i++){
            int m = tid + i*256;
            const float* em = E + m*10;
            float s = 0.f;
            #pragma unroll
            for (int d = 0; d < 10; d++) s += en[d]*em[d];
            v[i] = fmaxf(s, 0.f);
        }
        float mx = v[0];
        #pragma unroll
        for (int i = 1; i < 8; i++) mx = fmaxf(mx, v[i]);
        #pragma unroll
        for (int off = 32; off > 0; off >>= 1) mx = fmaxf(mx, __shfl_xor(mx, off));
        if (lane == 0) red[w] = mx;
        __syncthreads();
        mx = fmaxf(fmaxf(red[0], red[1]), fmaxf(red[2], red[3]));
        __syncthreads();
        float sum = 0.f;
        #pragma unroll
        for (int i = 0; i < 8; i++){ v[i] = __expf(v[i] - mx); sum += v[i]; }
        #pragma unroll
        for (int off = 32; off > 0; off >>= 1) sum += __shfl_xor(sum, off);
        if (lane == 0) red[4 + w] = sum;
        __syncthreads();
        sum = red[4] + red[5] + red[6] + red[7];
        float inv = 1.f / sum;
        #pragma unroll
        for (int i = 0; i < 8; i++){
            float p = v[i] * inv;
            u16 h, l; split_h(p, h, l);
            int ms = swz(n, tid + i*256);
            Sh[n*2048 + ms] = h;
            Sl[n*2048 + ms] = l;
        }
        return;
    }
    long idx = (long)(blockIdx.x - 2048)*256 + tid;
    if (idx < 491520){                               // gate w -> [jc][d][128 o][32 k]
        int kk = (int)(idx & 31);
        int o  = (int)((idx >> 5) & 127);
        int r2 = (int)(idx >> 12);                   // 0..119
        int d = r2 % 10, jc = r2 / 10;
        int j = jc*32 + kk;                          // 0..383
        int k = j >> 7, i = j & 127;
        float v = gwp[(((d*3 + k)*128) + i)*128 + o];
        wg[idx] = f2h(v);
    } else if (idx < 737280){                        // upd w -> [jc][d][64 o][32 k]
        long t = idx - 491520;
        int kk = (int)(t & 31);
        int o  = (int)((t >> 5) & 63);
        int r2 = (int)(t >> 11);                     // 0..119
        int d = r2 % 10, jc = r2 / 10;
        int j = jc*32 + kk;
        int k = j >> 7, i = j & 127;
        float v = uwp[(((d*3 + k)*128) + i)*64 + o];
        wu[t] = f2h(v);
    } else if (idx < 999424){                        // bias_g [2048][128]
        long t = idx - 737280; int n = (int)(t >> 7), o = (int)(t & 127);
        float s = 0.f;
        #pragma unroll
        for (int d = 0; d < 10; d++) s += E[n*10+d]*gbp[d*128+o];
        bg[t] = s;
    } else if (idx < 1130496){                       // bias_u [2048][64]
        long t = idx - 999424; int n = (int)(t >> 6), o = (int)(t & 63);
        float s = 0.f;
        #pragma unroll
        for (int d = 0; d < 10; d++) s += E[n*10+d]*ubp[d*64+o];
        bu[t] = s;
    } else if (idx < 5324800){                       // X_gate^T pack (single f16, swz)
        long t = idx - 1130496;
        int colG = (int)(t >> 11), m = (int)(t & 2047);
        int b = colG >> 7, c = colG & 127;
        float v = (c < 64) ? x[((long)(b*2048)+m)*64 + c]
                           : state[((long)(b*2048)+m)*64 + c - 64];
        xt[(long)colG*2048 + swz(colG, m)] = f2h(v);
    } else if (idx < 5332992){                       // lin_w [64 o][128 k] -> f16
        long t = idx - 5324800;
        lwt[t] = f2h(lw[t]);
    }
}

// =====================================================================
// Diffusion GEMM v4: A (S hi/lo) global->REGISTERS (no LDS round-trip;
// gemm was LDS-BW-bound: A was half the 2304 LDS-cyc/iter), B stays
// global_load_lds -> LDS (shared by all 4 waves). A reg double-buffered
// one 64-K step ahead (named X*/Y* sets, all compile-time indices).
// Identical operand values + MFMA order -> bit-exact (absmax canary).
// =====================================================================
template<int EPI>
__global__ __launch_bounds__(256) void k_gemm(
    const u16* __restrict__ Ah, const u16* __restrict__ Al,
    const u16* __restrict__ Bt,
    u16* __restrict__ Ot, float* __restrict__ Orow,
    const u16* __restrict__ Xt)
{
    __shared__ __attribute__((aligned(16))) u16 Bs[2][128*64];
    const int tid = threadIdx.x;
    // XCD-aware bijective tile mapping (8 XCDs x 8x8 sub-grid)
    const int xc = blockIdx.x & 7, ii = blockIdx.x >> 3;
    const int bm = ((xc & 3)*8 + (ii & 7)) << 6;     // 32 row-tiles
    const int bn = ((xc >> 2)*8 + (ii >> 3)) << 7;   // 16 col-tiles
    const int w = tid >> 6, lane = tid & 63;
    const int wm = (w & 1) << 5;                     // 32 rows per wave
    const int wn = (w >> 1) << 6;                    // 64 cols per wave
    const int lr = lane & 15, lk = lane >> 4;

    // B staging (linear LDS dest)
    const int srow = tid >> 3, scol = (tid & 7) << 3;
    const long b0 = (long)(bn + srow)*2048 + scol;
    const long b1 = b0 + 32*2048;
    const long b2 = b0 + 64*2048;
    const long b3 = b0 + 96*2048;
    const int l0 = tid*8, l1 = tid*8 + 2048;

    // swizzled chunk offsets (key = lr&7 for both A rows and B LDS rows)
    const int c0 = (lk ^ (lr & 7)) << 3;
    const int c1 = c0 ^ 32;

    // A per-lane global bases: rows (bm+wm+mi*16+lr)
    const long ab0 = (long)(bm + wm + lr)*2048;
    const long ab1 = ab0 + 16*2048;

#define STAGEB(BUF, K) do { \
        gll16(Bt + b0 + (K), &Bs[BUF][l0]); \
        gll16(Bt + b1 + (K), &Bs[BUF][l1]); \
        gll16(Bt + b2 + (K), &Bs[BUF][l0 + 4096]); \
        gll16(Bt + b3 + (K), &Bs[BUF][l1 + 4096]); \
    } while(0)

#define LOADA(P, K) do { \
        P##h00 = *(const s16x8*)(Ah + ab0 + (K) + c0); \
        P##h01 = *(const s16x8*)(Ah + ab0 + (K) + c1); \
        P##h10 = *(const s16x8*)(Ah + ab1 + (K) + c0); \
        P##h11 = *(const s16x8*)(Ah + ab1 + (K) + c1); \
        P##l00 = *(const s16x8*)(Al + ab0 + (K) + c0); \
        P##l01 = *(const s16x8*)(Al + ab0 + (K) + c1); \
        P##l10 = *(const s16x8*)(Al + ab1 + (K) + c0); \
        P##l11 = *(const s16x8*)(Al + ab1 + (K) + c1); \
    } while(0)

// one s2-half: 4 B-frag ds_reads, 8 hi MFMA then 8 lo MFMA (round-6 order)
#define HALF(BUF, CC, AH0, AH1, AL0, AL1) do { \
        const u16* bs_ = Bs[BUF]; \
        s16x8 bv0 = *(const s16x8*)&bs_[(wn +  0 + lr)*64 + (CC)]; \
        s16x8 bv1 = *(const s16x8*)&bs_[(wn + 16 + lr)*64 + (CC)]; \
        s16x8 bv2 = *(const s16x8*)&bs_[(wn + 32 + lr)*64 + (CC)]; \
        s16x8 bv3 = *(const s16x8*)&bs_[(wn + 48 + lr)*64 + (CC)]; \
        acc[0][0] = mfma16(AH0, bv0, acc[0][0]); \
        acc[0][1] = mfma16(AH0, bv1, acc[0][1]); \
        acc[0][2] = mfma16(AH0, bv2, acc[0][2]); \
        acc[0][3] = mfma16(AH0, bv3, acc[0][3]); \
        acc[1][0] = mfma16(AH1, bv0, acc[1][0]); \
        acc[1][1] = mfma16(AH1, bv1, acc[1][1]); \
        acc[1][2] = mfma16(AH1, bv2, acc[1][2]); \
        acc[1][3] = mfma16(AH1, bv3, acc[1][3]); \
        acc[0][0] = mfma16(AL0, bv0, acc[0][0]); \
        acc[0][1] = mfma16(AL0, bv1, acc[0][1]); \
        acc[0][2] = mfma16(AL0, bv2, acc[0][2]); \
        acc[0][3] = mfma16(AL0, bv3, acc[0][3]); \
        acc[1][0] = mfma16(AL1, bv0, acc[1][0]); \
        acc[1][1] = mfma16(AL1, bv1, acc[1][1]); \
        acc[1][2] = mfma16(AL1, bv2, acc[1][2]); \
        acc[1][3] = mfma16(AL1, bv3, acc[1][3]); \
    } while(0)

#define STEP(P, BUF) do { \
        HALF(BUF, c0, P##h00, P##h10, P##l00, P##l10); \
        HALF(BUF, c1, P##h01, P##h11, P##l01, P##l11); \
    } while(0)

    f32x4 acc[2][4];
    const f32x4 Z4 = {0.f, 0.f, 0.f, 0.f};
    #pragma unroll
    for (int i = 0; i < 2; i++)
        #pragma unroll
        for (int j = 0; j < 4; j++) acc[i][j] = Z4;

    s16x8 Xh00,Xh01,Xh10,Xh11,Xl00,Xl01,Xl10,Xl11;
    s16x8 Yh00,Yh01,Yh10,Yh11,Yl00,Yl01,Yl10,Yl11;

    STAGEB(0, 0);
    LOADA(X, 0);
    __syncthreads();                 // Bs[0] ready (drains A prefetch too)
    #pragma unroll 1
    for (int k0 = 0; k0 < 2048; k0 += 128){
        if (k0 + 64 < 2048){ STAGEB(1, k0 + 64); LOADA(Y, k0 + 64); }
        STEP(X, 0);
        __syncthreads();
        if (k0 + 128 < 2048){ STAGEB(0, k0 + 128); LOADA(X, k0 + 128); }
        STEP(Y, 1);
        __syncthreads();
    }
#undef STAGEB
#undef LOADA
#undef HALF
#undef STEP

    #pragma unroll
    for (int mi = 0; mi < 2; mi++){
        #pragma unroll
        for (int ni = 0; ni < 4; ni++){
            int i0 = bm + wm + mi*16 + lk*4;
            int j  = bn + wn + ni*16 + lr;
            f32x4 v = acc[mi][ni];
            if constexpr (EPI){
                u16x4 xh = *(const u16x4*)(Xt + (long)j*2048 + swz(j, i0));
                #pragma unroll
                for (int r = 0; r < 4; r++)
                    v[r] = 2.f*v[r] - h2f(xh[r]);
            }
            int bb = j >> 7, cc = j & 127;
            float* rp = Orow + ((long)bb*2048 + i0)*128 + cc;
            #pragma unroll
            for (int r = 0; r < 4; r++) rp[(long)r*128] = v[r];
            if constexpr (!EPI){
                u16x4 oh;
                #pragma unroll
                for (int r = 0; r < 4; r++) oh[r] = f2h(v[r]);
                *(u16x4*)(Ot + (long)j*2048 + swz(j, i0)) = oh;
            }
        }
    }
}

// =====================================================================
// Combine (round-6 proven, VERBATIM): out = sum_jc sum_d
// E[n,d]*(A_jc W[d]_jc) + bias. 256 thr, (256,2), d fully unrolled,
// triple-buffer W prefetch dist 2, zero-C first MFMA, VGPR 84.
// FUSE=1 (gate): fused zr = Zg@lw^T + candidate^T write.
// =====================================================================
template<int OFULL, int ACT, int FUSE>
__global__ __launch_bounds__(256, 2) void k_combine(
    const float* __restrict__ G1r, const float* __restrict__ G2r,
    const float* __restrict__ x, const float* __restrict__ second,
    const u16* __restrict__ W,
    const float* __restrict__ bias, const float* __restrict__ E,
    float* __restrict__ out, u16* __restrict__ XtT,
    const u16* __restrict__ lwt, const float* __restrict__ lb)
{
    constexpr int NO = OFULL/32;                 // o-frags per wave (4 gate, 2 upd)
    __shared__ u16 Ash[64*40], Asl[64*40];
    __shared__ float Et[640];
    __shared__ u16 Zh[FUSE ? 64*136 : 1];
    __shared__ u16 Zl[FUSE ? 64*136 : 1];
    const int tid = threadIdx.x, bid = blockIdx.x;
    const int b = bid >> 5, n0 = (bid & 31) << 6;
    const int w = tid >> 6, lane = tid & 63;
    const int wm = (w & 1)*32, wo = (w >> 1)*(OFULL/2);
    const int lr = lane & 15, lk = lane >> 4;

    for (int i = tid; i < 640; i += 256)
        Et[i] = E[(n0 + (i & 63))*10 + (i >> 6)];

    const f32x4 Z4 = {0.f, 0.f, 0.f, 0.f};
    f32x4 acc[2][NO];
    #pragma unroll
    for (int mi = 0; mi < 2; mi++)
        #pragma unroll
        for (int oi = 0; oi < NO; oi++) acc[mi][oi] = Z4;

    const long rowbase = (long)b*2048 + n0;
    const int laneoff = (wo + lr)*32 + lk*8;     // u16 offset within tile

    s16x8 pbh[3][NO];

    for (int jc = 0; jc < 12; jc++){
        // preload W tiles d=0,1 (independent of A; overlap staging+barrier)
        {
            const long t0 = (long)(jc*10 + 0)*OFULL*32;
            const long t1 = (long)(jc*10 + 1)*OFULL*32;
            #pragma unroll
            for (int oi = 0; oi < NO; oi++){
                pbh[0][oi] = *(const s16x8*)(W + t0 + laneoff + oi*16*32);
                pbh[1][oi] = *(const s16x8*)(W + t1 + laneoff + oi*16*32);
            }
        }
        __syncthreads();   // prior jc's A-frag reads are long done
        // ---- stage A (one 16B chunk per thread, f16 hi/lo) ----
        {
            const float* src; int stride;
            if (jc < 4){
                int col0 = jc*32;
                src = (col0 < 64) ? (x + rowbase*64 + col0)
                                  : (second + rowbase*64 + (col0 - 64));
                stride = 64;
            } else if (jc < 8){
                src = G1r + rowbase*128 + (jc-4)*32; stride = 128;
            } else {
                src = G2r + rowbase*128 + (jc-8)*32; stride = 128;
            }
            int row = tid >> 2, c8 = (tid & 3)*8;
            f32x4 s0 = *(const f32x4*)(src + (long)row*stride + c8);
            f32x4 s1 = *(const f32x4*)(src + (long)row*stride + c8 + 4);
            s16x8 vh, vl;
            #pragma unroll
            for (int t = 0; t < 4; t++){
                u16 h,l; split_h(s0[t], h, l); vh[t]=(short)h; vl[t]=(short)l;
            }
            #pragma unroll
            for (int t = 0; t < 4; t++){
                u16 h,l; split_h(s1[t], h, l); vh[4+t]=(short)h; vl[4+t]=(short)l;
            }
            *(s16x8*)&Ash[row*40 + c8] = vh;
            *(s16x8*)&Asl[row*40 + c8] = vl;
        }
        __syncthreads();

        s16x8 ah[2], al[2];
        #pragma unroll
        for (int mi = 0; mi < 2; mi++){
            ah[mi] = *(const s16x8*)&Ash[(wm + mi*16 + lr)*40 + lk*8];
            al[mi] = *(const s16x8*)&Asl[(wm + mi*16 + lr)*40 + lk*8];
        }

        #pragma unroll
        for (int d = 0; d < 10; d++){
            const int cur = d % 3;               // compile-time after unroll
            if (d < 8){                          // prefetch d+2 into slot (d+2)%3
                const int nx = (d + 2) % 3;
                const long t2 = (long)(jc*10 + d + 2)*OFULL*32;
                #pragma unroll
                for (int oi = 0; oi < NO; oi++)
                    pbh[nx][oi] = *(const s16x8*)(W + t2 + laneoff + oi*16*32);
            }
            f32x4 Cd[2][NO];
            #pragma unroll
            for (int mi = 0; mi < 2; mi++)
                #pragma unroll
                for (int oi = 0; oi < NO; oi++)
                    Cd[mi][oi] = mfma16(ah[mi], pbh[cur][oi], Z4);
            #pragma unroll
            for (int mi = 0; mi < 2; mi++)
                #pragma unroll
                for (int oi = 0; oi < NO; oi++)
                    Cd[mi][oi] = mfma16(al[mi], pbh[cur][oi], Cd[mi][oi]);
            #pragma unroll
            for (int mi = 0; mi < 2; mi++){
                f32x4 e4 = *(const f32x4*)&Et[d*64 + wm + mi*16 + lk*4];
                #pragma unroll
                for (int oi = 0; oi < NO; oi++) acc[mi][oi] += e4 * Cd[mi][oi];
            }
        }
    }

    if constexpr (!FUSE){
        #pragma unroll
        for (int mi = 0; mi < 2; mi++){
            #pragma unroll
            for (int oi = 0; oi < NO; oi++){
                int mrow = n0 + wm + mi*16 + lk*4;
                int o = wo + oi*16 + lr;
                #pragma unroll
                for (int r = 0; r < 4; r++){
                    float v = acc[mi][oi][r] + bias[(long)(mrow + r)*OFULL + o];
                    v = (ACT == 0) ? (1.f/(1.f + __expf(-v))) : tanhf(v);
                    out[((long)b*2048 + mrow + r)*OFULL + o] = v;
                }
            }
        }
    } else {
        // ---- fused: Zg = sigmoid(acc+bias) -> LDS limbs ----
        #pragma unroll
        for (int mi = 0; mi < 2; mi++){
            #pragma unroll
            for (int oi = 0; oi < NO; oi++){
                int lrow = wm + mi*16 + lk*4;
                int o = wo + oi*16 + lr;
                #pragma unroll
                for (int r = 0; r < 4; r++){
                    float v = acc[mi][oi][r] + bias[(long)(n0 + lrow + r)*OFULL + o];
                    v = 1.f/(1.f + __expf(-v));
                    u16 h, l; split_h(v, h, l);
                    Zh[(lrow + r)*136 + o] = h;
                    Zl[(lrow + r)*136 + o] = l;
                }
            }
        }
        __syncthreads();
        // ---- zr = Zg @ lw^T + lb ; wave w owns o-stripe w*16 ----
        f32x4 az[4];
        #pragma unroll
        for (int mi = 0; mi < 4; mi++) az[mi] = Z4;
        const int oz = w*16 + lr;
        #pragma unroll
        for (int ks = 0; ks < 4; ks++){
            s16x8 bw = *(const s16x8*)(lwt + oz*128 + ks*32 + lk*8);
            #pragma unroll
            for (int mi = 0; mi < 4; mi++){
                s16x8 zh = *(const s16x8*)&Zh[(mi*16 + lr)*136 + ks*32 + lk*8];
                az[mi] = mfma16(zh, bw, az[mi]);
            }
            #pragma unroll
            for (int mi = 0; mi < 4; mi++){
                s16x8 zl = *(const s16x8*)&Zl[(mi*16 + lr)*136 + ks*32 + lk*8];
                az[mi] = mfma16(zl, bw, az[mi]);
            }
        }
        const float lbv = lb[w*16 + lr];
        const int colG = b*128 + 64 + w*16 + lr;
        #pragma unroll
        for (int mi = 0; mi < 4; mi++){
            int mrow = n0 + mi*16 + lk*4;
            u16x4 tq;
            #pragma unroll
            for (int r = 0; r < 4; r++){
                float v = az[mi][r] + lbv;
                out[((long)b*2048 + mrow + r)*64 + w*16 + lr] = v;  // zr f32 rows
                tq[r] = f2h(v);
            }
            *(u16x4*)(XtT + (long)colG*2048 + swz(colG, mrow)) = tq; // candidate^T half
        }
    }
}

// =====================================================================
extern "C" void kernel_launch(void* const* d_in, const int* in_sizes, int n_in,
                              void* d_out, int out_size, void* d_ws, size_t ws_size,
                              hipStream_t stream)
{
    const float* x   = (const float*)d_in[0];
    const float* st  = (const float*)d_in[1];
    const float* E   = (const float*)d_in[2];
    const float* gwp = (const float*)d_in[3];
    const float* gbp = (const float*)d_in[4];
    const float* uwp = (const float*)d_in[5];
    const float* ubp = (const float*)d_in[6];
    const float* lw  = (const float*)d_in[7];
    const float* lb  = (const float*)d_in[8];
    float* out = (float*)d_out;
    char* ws = (char*)d_ws;

    const size_t MB8 = 8388608;
    u16*   Sh   = (u16*)(ws);                 // 8 MB
    u16*   Sl   = (u16*)(ws + 1*MB8);         // 8 MB
    u16*   Xt   = (u16*)(ws + 2*MB8);         // 8 MB (X^T gate -> candidate)
    u16*   G1t  = (u16*)(ws + 3*MB8);         // 8 MB
    float* G1row= (float*)(ws + 4*MB8);       // 16 MB
    float* G2row= (float*)(ws + 6*MB8);       // 16 MB
    float* zr   = (float*)(ws + 8*MB8);       // 8 MB
    char*  p    = ws + 9*MB8;
    u16* wg = (u16*)p;             p += 983040;
    u16* wu = (u16*)p;             p += 491520;
    float* bg = (float*)p;         p += 1048576;
    float* bu = (float*)p;         p += 524288;
    u16* lwt = (u16*)p;            p += 16384;

    // merged supports (2048 blocks) + prep (20832 blocks)
    k_prep<<<dim3(22880), dim3(256), 0, stream>>>(E, gwp, gbp, uwp, ubp, x, st, lw,
                                                  wg, wu, bg, bu, Xt, lwt, Sh, Sl);
    // gate diffusion
    k_gemm<0><<<dim3(512), dim3(256), 0, stream>>>(Sh, Sl, Xt, G1t, G1row,
                                                   (const u16*)nullptr);
    k_gemm<1><<<dim3(512), dim3(256), 0, stream>>>(Sh, Sl, G1t, (u16*)nullptr, G2row,
                                                   Xt);
    // gate combine -> zr (fused lin) + candidate^T zr-half into Xt
    k_combine<128,0,1><<<dim3(512), dim3(256), 0, stream>>>(G1row, G2row, x, st,
                                                            wg, bg, E, zr, Xt, lwt, lb);
    // update diffusion (Xt now = candidate^T)
    k_gemm<0><<<dim3(512), dim3(256), 0, stream>>>(Sh, Sl, Xt, G1t, G1row,
                                                   (const u16*)nullptr);
    k_gemm<1><<<dim3(512), dim3(256), 0, stream>>>(Sh, Sl, G1t, (u16*)nullptr, G2row,
                                                   Xt);
    // update combine -> out (tanh)
    k_combine<64,1,0><<<dim3(512), dim3(256), 0, stream>>>(G1row, G2row, x, zr,
                                                           wu, bu, E, out,
                                                           (u16*)nullptr,
                                                           (const u16*)nullptr,
                                                           (const float*)nullptr);
}

// Round 9
// 391.586 us; speedup vs baseline: 1.0519x; 1.0519x over previous
//
#include <hip/hip_runtime.h>

typedef unsigned short u16;
typedef short s16x8 __attribute__((ext_vector_type(8)));
typedef _Float16 h16x8 __attribute__((ext_vector_type(8)));
typedef float f32x4 __attribute__((ext_vector_type(4)));
typedef u16 u16x4 __attribute__((ext_vector_type(4)));

#define DEV static __device__ __forceinline__

// ---------- f16 limb helpers (RTNE via v_cvt_f16_f32) ----------
DEV u16 f2h(float x){ union { _Float16 h; u16 u; } v; v.h = (_Float16)x; return v.u; }
DEV float h2f(u16 u){ union { u16 u; _Float16 h; } v; v.u = u; return (float)v.h; }
DEV void split_h(float x, u16& h, u16& l){
    h = f2h(x);
    l = f2h(x - h2f(h));
}
DEV h16x8 H8(s16x8 v){ union { s16x8 s; h16x8 h; } u; u.s = v; return u.h; }
DEV f32x4 mfma16(s16x8 a, s16x8 b, f32x4 c){
    return __builtin_amdgcn_mfma_f32_16x16x32_f16(H8(a), H8(b), c, 0, 0, 0);
}

// ---------- t-layout chunk swizzle (bits 3-5 of m XOR row&7) ----------
DEV int swz(int r, int m){ return (m & ~0x38) | ((((m >> 3) ^ r) & 7) << 3); }

// global -> LDS direct (16B per lane)
DEV void gll16(const u16* g, u16* l){
    __builtin_amdgcn_global_load_lds((const __attribute__((address_space(1))) void*)g,
                                     (__attribute__((address_space(3))) void*)l, 16, 0, 0);
}

// =====================================================================
// K_prep (merged): blocks 0..2047 = supports softmax rows; rest = prep.
// =====================================================================
__global__ __launch_bounds__(256) void k_prep(const float* __restrict__ E,
    const float* __restrict__ gwp, const float* __restrict__ gbp,
    const float* __restrict__ uwp, const float* __restrict__ ubp,
    const float* __restrict__ x,   const float* __restrict__ state,
    const float* __restrict__ lw,
    u16* __restrict__ wg, u16* __restrict__ wu,
    float* __restrict__ bg, float* __restrict__ bu,
    u16* __restrict__ xt, u16* __restrict__ lwt,
    u16* __restrict__ Sh, u16* __restrict__ Sl)
{
    __shared__ float red[8];
    const int tid = threadIdx.x;
    if (blockIdx.x < 2048){
        const int n = blockIdx.x;
        const int w = tid >> 6, lane = tid & 63;
        float en[10];
        #pragma unroll
        for (int d = 0; d < 10; d++) en[d] = E[n*10 + d];
        float v[8];
        #pragma unroll
        for (int i = 0; i < 8; i++){
            int m = tid + i*256;
            const float* em = E + m*10;
            float s = 0.f;
            #pragma unroll
            for (int d = 0; d < 10; d++) s += en[d]*em[d];
            v[i] = fmaxf(s, 0.f);
        }
        float mx = v[0];
        #pragma unroll
        for (int i = 1; i < 8; i++) mx = fmaxf(mx, v[i]);
        #pragma unroll
        for (int off = 32; off > 0; off >>= 1) mx = fmaxf(mx, __shfl_xor(mx, off));
        if (lane == 0) red[w] = mx;
        __syncthreads();
        mx = fmaxf(fmaxf(red[0], red[1]), fmaxf(red[2], red[3]));
        __syncthreads();
        float sum = 0.f;
        #pragma unroll
        for (int i = 0; i < 8; i++){ v[i] = __expf(v[i] - mx); sum += v[i]; }
        #pragma unroll
        for (int off = 32; off > 0; off >>= 1) sum += __shfl_xor(sum, off);
        if (lane == 0) red[4 + w] = sum;
        __syncthreads();
        sum = red[4] + red[5] + red[6] + red[7];
        float inv = 1.f / sum;
        #pragma unroll
        for (int i = 0; i < 8; i++){
            float p = v[i] * inv;
            u16 h, l; split_h(p, h, l);
            int ms = swz(n, tid + i*256);
            Sh[n*2048 + ms] = h;
            Sl[n*2048 + ms] = l;
        }
        return;
    }
    long idx = (long)(blockIdx.x - 2048)*256 + tid;
    if (idx < 491520){                               // gate w -> [jc][d][128 o][32 k]
        int kk = (int)(idx & 31);
        int o  = (int)((idx >> 5) & 127);
        int r2 = (int)(idx >> 12);                   // 0..119
        int d = r2 % 10, jc = r2 / 10;
        int j = jc*32 + kk;                          // 0..383
        int k = j >> 7, i = j & 127;
        float v = gwp[(((d*3 + k)*128) + i)*128 + o];
        wg[idx] = f2h(v);
    } else if (idx < 737280){                        // upd w -> [jc][d][64 o][32 k]
        long t = idx - 491520;
        int kk = (int)(t & 31);
        int o  = (int)((t >> 5) & 63);
        int r2 = (int)(t >> 11);                     // 0..119
        int d = r2 % 10, jc = r2 / 10;
        int j = jc*32 + kk;
        int k = j >> 7, i = j & 127;
        float v = uwp[(((d*3 + k)*128) + i)*64 + o];
        wu[t] = f2h(v);
    } else if (idx < 999424){                        // bias_g [2048][128]
        long t = idx - 737280; int n = (int)(t >> 7), o = (int)(t & 127);
        float s = 0.f;
        #pragma unroll
        for (int d = 0; d < 10; d++) s += E[n*10+d]*gbp[d*128+o];
        bg[t] = s;
    } else if (idx < 1130496){                       // bias_u [2048][64]
        long t = idx - 999424; int n = (int)(t >> 6), o = (int)(t & 63);
        float s = 0.f;
        #pragma unroll
        for (int d = 0; d < 10; d++) s += E[n*10+d]*ubp[d*64+o];
        bu[t] = s;
    } else if (idx < 5324800){                       // X_gate^T pack (single f16, swz)
        long t = idx - 1130496;
        int colG = (int)(t >> 11), m = (int)(t & 2047);
        int b = colG >> 7, c = colG & 127;
        float v = (c < 64) ? x[((long)(b*2048)+m)*64 + c]
                           : state[((long)(b*2048)+m)*64 + c - 64];
        xt[(long)colG*2048 + swz(colG, m)] = f2h(v);
    } else if (idx < 5332992){                       // lin_w [64 o][128 k] -> f16
        long t = idx - 5324800;
        lwt[t] = f2h(lw[t]);
    }
}

// =====================================================================
// Diffusion GEMM (round-6 proven structure) + K-SPLIT (PH=0: K 0..1024,
// PH=1: K 1024..2048). Rationale: all 512 blocks co-resident; 8x8 XCD
// sub-grid footprint = 8 A-tiles (4MB, 2-limb) + 8 B-tiles (4MB) = 8MB
// vs 4MB L2/XCD. K=1024 halves tile bytes -> 4MB, L2-fit. The f32 acc
// round-trips through Orow: f32 reg -> f32 mem -> resume is EXACT and
// MFMA order unchanged -> bit-identical (absmax canary 0.01513672).
// PH0 epilogue: plain Orow store. PH1: (EPI) transform + final stores.
// =====================================================================
template<int EPI, int PH>
__global__ __launch_bounds__(256) void k_gemm(
    const u16* __restrict__ Ah, const u16* __restrict__ Al,
    const u16* __restrict__ Bt,
    u16* __restrict__ Ot, float* __restrict__ Orow,
    const u16* __restrict__ Xt)
{
    __shared__ __attribute__((aligned(16))) u16 AsH[2][64*64];
    __shared__ __attribute__((aligned(16))) u16 AsL[2][64*64];
    __shared__ __attribute__((aligned(16))) u16 Bs[2][128*64];
    const int tid = threadIdx.x;
    // XCD-aware bijective tile mapping (8 XCDs x 8x8 sub-grid)
    const int xc = blockIdx.x & 7, ii = blockIdx.x >> 3;
    const int bm = ((xc & 3)*8 + (ii & 7)) << 6;     // 32 row-tiles
    const int bn = ((xc >> 2)*8 + (ii >> 3)) << 7;   // 16 col-tiles
    const int w = tid >> 6, lane = tid & 63;
    const int wm = (w & 1) << 5;                     // 32 rows per wave
    const int wn = (w >> 1) << 6;                    // 64 cols per wave
    const int lr = lane & 15, lk = lane >> 4;

    const int srow = tid >> 3, scol = (tid & 7) << 3;
    const long a0 = (long)(bm + srow)*2048 + scol;
    const long a1 = a0 + 32*2048;
    const long b0 = (long)(bn + srow)*2048 + scol;
    const long b1 = b0 + 32*2048;
    const long b2 = b0 + 64*2048;
    const long b3 = b0 + 96*2048;
    const int l0 = tid*8, l1 = tid*8 + 2048;

    const int c0 = (lk ^ (lr & 7)) << 3;
    const int c1 = c0 ^ 32;

    constexpr int K0 = PH*1024, KEND = K0 + 1024;

#define STAGE(B, K) do { \
        gll16(Ah + a0 + (K), &AsH[B][l0]); \
        gll16(Ah + a1 + (K), &AsH[B][l1]); \
        gll16(Al + a0 + (K), &AsL[B][l0]); \
        gll16(Al + a1 + (K), &AsL[B][l1]); \
        gll16(Bt + b0 + (K), &Bs[B][l0]); \
        gll16(Bt + b1 + (K), &Bs[B][l1]); \
        gll16(Bt + b2 + (K), &Bs[B][l0 + 4096]); \
        gll16(Bt + b3 + (K), &Bs[B][l1 + 4096]); \
    } while(0)

    f32x4 acc[2][4];
    if constexpr (PH == 0){
        const f32x4 Z4 = {0.f, 0.f, 0.f, 0.f};
        #pragma unroll
        for (int i = 0; i < 2; i++)
            #pragma unroll
            for (int j = 0; j < 4; j++) acc[i][j] = Z4;
    } else {
        // resume from phase-0 partial sums (exact f32 round-trip)
        #pragma unroll
        for (int mi = 0; mi < 2; mi++)
            #pragma unroll
            for (int ni = 0; ni < 4; ni++){
                int i0 = bm + wm + mi*16 + lk*4;
                int j  = bn + wn + ni*16 + lr;
                int bb = j >> 7, cc = j & 127;
                const float* rp = Orow + ((long)bb*2048 + i0)*128 + cc;
                #pragma unroll
                for (int r = 0; r < 4; r++) acc[mi][ni][r] = rp[(long)r*128];
            }
    }

    STAGE(0, K0);
    __syncthreads();
    int cur = 0;
    for (int k0 = K0; k0 < KEND; k0 += 64){
        if (k0 + 64 < KEND) STAGE(cur ^ 1, k0 + 64);
        const u16* ah = AsH[cur];
        const u16* al = AsL[cur];
        const u16* bs = Bs[cur];
        #pragma unroll
        for (int s2 = 0; s2 < 2; s2++){
            const int cc = s2 ? c1 : c0;
            s16x8 bfv[4], af[2];
            #pragma unroll
            for (int ni = 0; ni < 4; ni++)
                bfv[ni] = *(const s16x8*)&bs[(wn + ni*16 + lr)*64 + cc];
            #pragma unroll
            for (int mi = 0; mi < 2; mi++)
                af[mi] = *(const s16x8*)&ah[(wm + mi*16 + lr)*64 + cc];
            #pragma unroll
            for (int mi = 0; mi < 2; mi++)
                #pragma unroll
                for (int ni = 0; ni < 4; ni++)
                    acc[mi][ni] = mfma16(af[mi], bfv[ni], acc[mi][ni]);
            #pragma unroll
            for (int mi = 0; mi < 2; mi++)
                af[mi] = *(const s16x8*)&al[(wm + mi*16 + lr)*64 + cc];
            #pragma unroll
            for (int mi = 0; mi < 2; mi++)
                #pragma unroll
                for (int ni = 0; ni < 4; ni++)
                    acc[mi][ni] = mfma16(af[mi], bfv[ni], acc[mi][ni]);
        }
        __syncthreads();
        cur ^= 1;
    }
#undef STAGE

    #pragma unroll
    for (int mi = 0; mi < 2; mi++){
        #pragma unroll
        for (int ni = 0; ni < 4; ni++){
            int i0 = bm + wm + mi*16 + lk*4;
            int j  = bn + wn + ni*16 + lr;
            f32x4 v = acc[mi][ni];
            if constexpr (PH == 1 && EPI){
                u16x4 xh = *(const u16x4*)(Xt + (long)j*2048 + swz(j, i0));
                #pragma unroll
                for (int r = 0; r < 4; r++)
                    v[r] = 2.f*v[r] - h2f(xh[r]);
            }
            int bb = j >> 7, cc = j & 127;
            float* rp = Orow + ((long)bb*2048 + i0)*128 + cc;
            #pragma unroll
            for (int r = 0; r < 4; r++) rp[(long)r*128] = v[r];
            if constexpr (PH == 1 && !EPI){
                u16x4 oh;
                #pragma unroll
                for (int r = 0; r < 4; r++) oh[r] = f2h(v[r]);
                *(u16x4*)(Ot + (long)j*2048 + swz(j, i0)) = oh;
            }
        }
    }
}

// =====================================================================
// Combine (round-6 proven, VERBATIM): out = sum_jc sum_d
// E[n,d]*(A_jc W[d]_jc) + bias. 256 thr, (256,2), d fully unrolled,
// triple-buffer W prefetch dist 2, zero-C first MFMA, VGPR 84.
// FUSE=1 (gate): fused zr = Zg@lw^T + candidate^T write.
// =====================================================================
template<int OFULL, int ACT, int FUSE>
__global__ __launch_bounds__(256, 2) void k_combine(
    const float* __restrict__ G1r, const float* __restrict__ G2r,
    const float* __restrict__ x, const float* __restrict__ second,
    const u16* __restrict__ W,
    const float* __restrict__ bias, const float* __restrict__ E,
    float* __restrict__ out, u16* __restrict__ XtT,
    const u16* __restrict__ lwt, const float* __restrict__ lb)
{
    constexpr int NO = OFULL/32;                 // o-frags per wave (4 gate, 2 upd)
    __shared__ u16 Ash[64*40], Asl[64*40];
    __shared__ float Et[640];
    __shared__ u16 Zh[FUSE ? 64*136 : 1];
    __shared__ u16 Zl[FUSE ? 64*136 : 1];
    const int tid = threadIdx.x, bid = blockIdx.x;
    const int b = bid >> 5, n0 = (bid & 31) << 6;
    const int w = tid >> 6, lane = tid & 63;
    const int wm = (w & 1)*32, wo = (w >> 1)*(OFULL/2);
    const int lr = lane & 15, lk = lane >> 4;

    for (int i = tid; i < 640; i += 256)
        Et[i] = E[(n0 + (i & 63))*10 + (i >> 6)];

    const f32x4 Z4 = {0.f, 0.f, 0.f, 0.f};
    f32x4 acc[2][NO];
    #pragma unroll
    for (int mi = 0; mi < 2; mi++)
        #pragma unroll
        for (int oi = 0; oi < NO; oi++) acc[mi][oi] = Z4;

    const long rowbase = (long)b*2048 + n0;
    const int laneoff = (wo + lr)*32 + lk*8;     // u16 offset within tile

    s16x8 pbh[3][NO];

    for (int jc = 0; jc < 12; jc++){
        // preload W tiles d=0,1 (independent of A; overlap staging+barrier)
        {
            const long t0 = (long)(jc*10 + 0)*OFULL*32;
            const long t1 = (long)(jc*10 + 1)*OFULL*32;
            #pragma unroll
            for (int oi = 0; oi < NO; oi++){
                pbh[0][oi] = *(const s16x8*)(W + t0 + laneoff + oi*16*32);
                pbh[1][oi] = *(const s16x8*)(W + t1 + laneoff + oi*16*32);
            }
        }
        __syncthreads();   // prior jc's A-frag reads are long done
        // ---- stage A (one 16B chunk per thread, f16 hi/lo) ----
        {
            const float* src; int stride;
            if (jc < 4){
                int col0 = jc*32;
                src = (col0 < 64) ? (x + rowbase*64 + col0)
                                  : (second + rowbase*64 + (col0 - 64));
                stride = 64;
            } else if (jc < 8){
                src = G1r + rowbase*128 + (jc-4)*32; stride = 128;
            } else {
                src = G2r + rowbase*128 + (jc-8)*32; stride = 128;
            }
            int row = tid >> 2, c8 = (tid & 3)*8;
            f32x4 s0 = *(const f32x4*)(src + (long)row*stride + c8);
            f32x4 s1 = *(const f32x4*)(src + (long)row*stride + c8 + 4);
            s16x8 vh, vl;
            #pragma unroll
            for (int t = 0; t < 4; t++){
                u16 h,l; split_h(s0[t], h, l); vh[t]=(short)h; vl[t]=(short)l;
            }
            #pragma unroll
            for (int t = 0; t < 4; t++){
                u16 h,l; split_h(s1[t], h, l); vh[4+t]=(short)h; vl[4+t]=(short)l;
            }
            *(s16x8*)&Ash[row*40 + c8] = vh;
            *(s16x8*)&Asl[row*40 + c8] = vl;
        }
        __syncthreads();

        s16x8 ah[2], al[2];
        #pragma unroll
        for (int mi = 0; mi < 2; mi++){
            ah[mi] = *(const s16x8*)&Ash[(wm + mi*16 + lr)*40 + lk*8];
            al[mi] = *(const s16x8*)&Asl[(wm + mi*16 + lr)*40 + lk*8];
        }

        #pragma unroll
        for (int d = 0; d < 10; d++){
            const int cur = d % 3;               // compile-time after unroll
            if (d < 8){                          // prefetch d+2 into slot (d+2)%3
                const int nx = (d + 2) % 3;
                const long t2 = (long)(jc*10 + d + 2)*OFULL*32;
                #pragma unroll
                for (int oi = 0; oi < NO; oi++)
                    pbh[nx][oi] = *(const s16x8*)(W + t2 + laneoff + oi*16*32);
            }
            f32x4 Cd[2][NO];
            #pragma unroll
            for (int mi = 0; mi < 2; mi++)
                #pragma unroll
                for (int oi = 0; oi < NO; oi++)
                    Cd[mi][oi] = mfma16(ah[mi], pbh[cur][oi], Z4);
            #pragma unroll
            for (int mi = 0; mi < 2; mi++)
                #pragma unroll
                for (int oi = 0; oi < NO; oi++)
                    Cd[mi][oi] = mfma16(al[mi], pbh[cur][oi], Cd[mi][oi]);
            #pragma unroll
            for (int mi = 0; mi < 2; mi++){
                f32x4 e4 = *(const f32x4*)&Et[d*64 + wm + mi*16 + lk*4];
                #pragma unroll
                for (int oi = 0; oi < NO; oi++) acc[mi][oi] += e4 * Cd[mi][oi];
            }
        }
    }

    if constexpr (!FUSE){
        #pragma unroll
        for (int mi = 0; mi < 2; mi++){
            #pragma unroll
            for (int oi = 0; oi < NO; oi++){
                int mrow = n0 + wm + mi*16 + lk*4;
                int o = wo + oi*16 + lr;
                #pragma unroll
                for (int r = 0; r < 4; r++){
                    float v = acc[mi][oi][r] + bias[(long)(mrow + r)*OFULL + o];
                    v = (ACT == 0) ? (1.f/(1.f + __expf(-v))) : tanhf(v);
                    out[((long)b*2048 + mrow + r)*OFULL + o] = v;
                }
            }
        }
    } else {
        // ---- fused: Zg = sigmoid(acc+bias) -> LDS limbs ----
        #pragma unroll
        for (int mi = 0; mi < 2; mi++){
            #pragma unroll
            for (int oi = 0; oi < NO; oi++){
                int lrow = wm + mi*16 + lk*4;
                int o = wo + oi*16 + lr;
                #pragma unroll
                for (int r = 0; r < 4; r++){
                    float v = acc[mi][oi][r] + bias[(long)(n0 + lrow + r)*OFULL + o];
                    v = 1.f/(1.f + __expf(-v));
                    u16 h, l; split_h(v, h, l);
                    Zh[(lrow + r)*136 + o] = h;
                    Zl[(lrow + r)*136 + o] = l;
                }
            }
        }
        __syncthreads();
        // ---- zr = Zg @ lw^T + lb ; wave w owns o-stripe w*16 ----
        f32x4 az[4];
        #pragma unroll
        for (int mi = 0; mi < 4; mi++) az[mi] = Z4;
        const int oz = w*16 + lr;
        #pragma unroll
        for (int ks = 0; ks < 4; ks++){
            s16x8 bw = *(const s16x8*)(lwt + oz*128 + ks*32 + lk*8);
            #pragma unroll
            for (int mi = 0; mi < 4; mi++){
                s16x8 zh = *(const s16x8*)&Zh[(mi*16 + lr)*136 + ks*32 + lk*8];
                az[mi] = mfma16(zh, bw, az[mi]);
            }
            #pragma unroll
            for (int mi = 0; mi < 4; mi++){
                s16x8 zl = *(const s16x8*)&Zl[(mi*16 + lr)*136 + ks*32 + lk*8];
                az[mi] = mfma16(zl, bw, az[mi]);
            }
        }
        const float lbv = lb[w*16 + lr];
        const int colG = b*128 + 64 + w*16 + lr;
        #pragma unroll
        for (int mi = 0; mi < 4; mi++){
            int mrow = n0 + mi*16 + lk*4;
            u16x4 tq;
            #pragma unroll
            for (int r = 0; r < 4; r++){
                float v = az[mi][r] + lbv;
                out[((long)b*2048 + mrow + r)*64 + w*16 + lr] = v;  // zr f32 rows
                tq[r] = f2h(v);
            }
            *(u16x4*)(XtT + (long)colG*2048 + swz(colG, mrow)) = tq; // candidate^T half
        }
    }
}

// =====================================================================
extern "C" void kernel_launch(void* const* d_in, const int* in_sizes, int n_in,
                              void* d_out, int out_size, void* d_ws, size_t ws_size,
                              hipStream_t stream)
{
    const float* x   = (const float*)d_in[0];
    const float* st  = (const float*)d_in[1];
    const float* E   = (const float*)d_in[2];
    const float* gwp = (const float*)d_in[3];
    const float* gbp = (const float*)d_in[4];
    const float* uwp = (const float*)d_in[5];
    const float* ubp = (const float*)d_in[6];
    const float* lw  = (const float*)d_in[7];
    const float* lb  = (const float*)d_in[8];
    float* out = (float*)d_out;
    char* ws = (char*)d_ws;

    const size_t MB8 = 8388608;
    u16*   Sh   = (u16*)(ws);                 // 8 MB
    u16*   Sl   = (u16*)(ws + 1*MB8);         // 8 MB
    u16*   Xt   = (u16*)(ws + 2*MB8);         // 8 MB (X^T gate -> candidate)
    u16*   G1t  = (u16*)(ws + 3*MB8);         // 8 MB
    float* G1row= (float*)(ws + 4*MB8);       // 16 MB
    float* G2row= (float*)(ws + 6*MB8);       // 16 MB
    float* zr   = (float*)(ws + 8*MB8);       // 8 MB
    char*  p    = ws + 9*MB8;
    u16* wg = (u16*)p;             p += 983040;
    u16* wu = (u16*)p;             p += 491520;
    float* bg = (float*)p;         p += 1048576;
    float* bu = (float*)p;         p += 524288;
    u16* lwt = (u16*)p;            p += 16384;

    // merged supports (2048 blocks) + prep (20832 blocks)
    k_prep<<<dim3(22880), dim3(256), 0, stream>>>(E, gwp, gbp, uwp, ubp, x, st, lw,
                                                  wg, wu, bg, bu, Xt, lwt, Sh, Sl);
    // gate diffusion (K-split: each logical gemm = 2 dispatches, L2-fit)
    k_gemm<0,0><<<dim3(512), dim3(256), 0, stream>>>(Sh, Sl, Xt, G1t, G1row,
                                                     (const u16*)nullptr);
    k_gemm<0,1><<<dim3(512), dim3(256), 0, stream>>>(Sh, Sl, Xt, G1t, G1row,
                                                     (const u16*)nullptr);
    k_gemm<1,0><<<dim3(512), dim3(256), 0, stream>>>(Sh, Sl, G1t, (u16*)nullptr,
                                                     G2row, Xt);
    k_gemm<1,1><<<dim3(512), dim3(256), 0, stream>>>(Sh, Sl, G1t, (u16*)nullptr,
                                                     G2row, Xt);
    // gate combine -> zr (fused lin) + candidate^T zr-half into Xt
    k_combine<128,0,1><<<dim3(512), dim3(256), 0, stream>>>(G1row, G2row, x, st,
                                                            wg, bg, E, zr, Xt, lwt, lb);
    // update diffusion (Xt now = candidate^T)
    k_gemm<0,0><<<dim3(512), dim3(256), 0, stream>>>(Sh, Sl, Xt, G1t, G1row,
                                                     (const u16*)nullptr);
    k_gemm<0,1><<<dim3(512), dim3(256), 0, stream>>>(Sh, Sl, Xt, G1t, G1row,
                                                     (const u16*)nullptr);
    k_gemm<1,0><<<dim3(512), dim3(256), 0, stream>>>(Sh, Sl, G1t, (u16*)nullptr,
                                                     G2row, Xt);
    k_gemm<1,1><<<dim3(512), dim3(256), 0, stream>>>(Sh, Sl, G1t, (u16*)nullptr,
                                                     G2row, Xt);
    // update combine -> out (tanh)
    k_combine<64,1,0><<<dim3(512), dim3(256), 0, stream>>>(G1row, G2row, x, zr,
                                                           wu, bu, E, out,
                                                           (u16*)nullptr,
                                                           (const u16*)nullptr,
                                                           (const float*)nullptr);
}

// Round 10
// 374.082 us; speedup vs baseline: 1.1011x; 1.0468x over previous
//
#include <hip/hip_runtime.h>

typedef unsigned short u16;
typedef short s16x8 __attribute__((ext_vector_type(8)));
typedef _Float16 h16x8 __attribute__((ext_vector_type(8)));
typedef float f32x4 __attribute__((ext_vector_type(4)));
typedef float f32x16 __attribute__((ext_vector_type(16)));
typedef u16 u16x4 __attribute__((ext_vector_type(4)));

#define DEV static __device__ __forceinline__

// ---------- f16 limb helpers (RTNE via v_cvt_f16_f32) ----------
DEV u16 f2h(float x){ union { _Float16 h; u16 u; } v; v.h = (_Float16)x; return v.u; }
DEV float h2f(u16 u){ union { u16 u; _Float16 h; } v; v.u = u; return (float)v.h; }
DEV void split_h(float x, u16& h, u16& l){
    h = f2h(x);
    l = f2h(x - h2f(h));
}
DEV h16x8 H8(s16x8 v){ union { s16x8 s; h16x8 h; } u; u.s = v; return u.h; }
DEV f32x4 mfma16(s16x8 a, s16x8 b, f32x4 c){
    return __builtin_amdgcn_mfma_f32_16x16x32_f16(H8(a), H8(b), c, 0, 0, 0);
}
DEV f32x16 mfma32(s16x8 a, s16x8 b, f32x16 c){
    return __builtin_amdgcn_mfma_f32_32x32x16_f16(H8(a), H8(b), c, 0, 0, 0);
}

// ---------- t-layout chunk swizzle (bits 3-5 of m XOR row&7) ----------
DEV int swz(int r, int m){ return (m & ~0x38) | ((((m >> 3) ^ r) & 7) << 3); }

// global -> LDS direct (16B per lane)
DEV void gll16(const u16* g, u16* l){
    __builtin_amdgcn_global_load_lds((const __attribute__((address_space(1))) void*)g,
                                     (__attribute__((address_space(3))) void*)l, 16, 0, 0);
}

// =====================================================================
// K_prep (merged): blocks 0..2047 = supports softmax rows; rest = prep.
// =====================================================================
__global__ __launch_bounds__(256) void k_prep(const float* __restrict__ E,
    const float* __restrict__ gwp, const float* __restrict__ gbp,
    const float* __restrict__ uwp, const float* __restrict__ ubp,
    const float* __restrict__ x,   const float* __restrict__ state,
    const float* __restrict__ lw,
    u16* __restrict__ wg, u16* __restrict__ wu,
    float* __restrict__ bg, float* __restrict__ bu,
    u16* __restrict__ xt, u16* __restrict__ lwt,
    u16* __restrict__ Sh, u16* __restrict__ Sl)
{
    __shared__ float red[8];
    const int tid = threadIdx.x;
    if (blockIdx.x < 2048){
        const int n = blockIdx.x;
        const int w = tid >> 6, lane = tid & 63;
        float en[10];
        #pragma unroll
        for (int d = 0; d < 10; d++) en[d] = E[n*10 + d];
        float v[8];
        #pragma unroll
        for (int i = 0; i < 8; i++){
            int m = tid + i*256;
            const float* em = E + m*10;
            float s = 0.f;
            #pragma unroll
            for (int d = 0; d < 10; d++) s += en[d]*em[d];
            v[i] = fmaxf(s, 0.f);
        }
        float mx = v[0];
        #pragma unroll
        for (int i = 1; i < 8; i++) mx = fmaxf(mx, v[i]);
        #pragma unroll
        for (int off = 32; off > 0; off >>= 1) mx = fmaxf(mx, __shfl_xor(mx, off));
        if (lane == 0) red[w] = mx;
        __syncthreads();
        mx = fmaxf(fmaxf(red[0], red[1]), fmaxf(red[2], red[3]));
        __syncthreads();
        float sum = 0.f;
        #pragma unroll
        for (int i = 0; i < 8; i++){ v[i] = __expf(v[i] - mx); sum += v[i]; }
        #pragma unroll
        for (int off = 32; off > 0; off >>= 1) sum += __shfl_xor(sum, off);
        if (lane == 0) red[4 + w] = sum;
        __syncthreads();
        sum = red[4] + red[5] + red[6] + red[7];
        float inv = 1.f / sum;
        #pragma unroll
        for (int i = 0; i < 8; i++){
            float p = v[i] * inv;
            u16 h, l; split_h(p, h, l);
            int ms = swz(n, tid + i*256);
            Sh[n*2048 + ms] = h;
            Sl[n*2048 + ms] = l;
        }
        return;
    }
    long idx = (long)(blockIdx.x - 2048)*256 + tid;
    if (idx < 491520){                               // gate w -> [jc][d][128 o][32 k]
        int kk = (int)(idx & 31);
        int o  = (int)((idx >> 5) & 127);
        int r2 = (int)(idx >> 12);                   // 0..119
        int d = r2 % 10, jc = r2 / 10;
        int j = jc*32 + kk;                          // 0..383
        int k = j >> 7, i = j & 127;
        float v = gwp[(((d*3 + k)*128) + i)*128 + o];
        wg[idx] = f2h(v);
    } else if (idx < 737280){                        // upd w -> [jc][d][64 o][32 k]
        long t = idx - 491520;
        int kk = (int)(t & 31);
        int o  = (int)((t >> 5) & 63);
        int r2 = (int)(t >> 11);                     // 0..119
        int d = r2 % 10, jc = r2 / 10;
        int j = jc*32 + kk;
        int k = j >> 7, i = j & 127;
        float v = uwp[(((d*3 + k)*128) + i)*64 + o];
        wu[t] = f2h(v);
    } else if (idx < 999424){                        // bias_g [2048][128]
        long t = idx - 737280; int n = (int)(t >> 7), o = (int)(t & 127);
        float s = 0.f;
        #pragma unroll
        for (int d = 0; d < 10; d++) s += E[n*10+d]*gbp[d*128+o];
        bg[t] = s;
    } else if (idx < 1130496){                       // bias_u [2048][64]
        long t = idx - 999424; int n = (int)(t >> 6), o = (int)(t & 63);
        float s = 0.f;
        #pragma unroll
        for (int d = 0; d < 10; d++) s += E[n*10+d]*ubp[d*64+o];
        bu[t] = s;
    } else if (idx < 5324800){                       // X_gate^T pack (single f16, swz)
        long t = idx - 1130496;
        int colG = (int)(t >> 11), m = (int)(t & 2047);
        int b = colG >> 7, c = colG & 127;
        float v = (c < 64) ? x[((long)(b*2048)+m)*64 + c]
                           : state[((long)(b*2048)+m)*64 + c - 64];
        xt[(long)colG*2048 + swz(colG, m)] = f2h(v);
    } else if (idx < 5332992){                       // lin_w [64 o][128 k] -> f16
        long t = idx - 5324800;
        lwt[t] = f2h(lw[t]);
    }
}

// =====================================================================
// Diffusion GEMM v5: round-6 staging/loop structure, inner math switched
// 16x16x32 -> 32x32x16 f16 MFMA. Same per-lane 16B fragment feeds 2x the
// FLOP -> ds_read_b128 count HALVED (16 vs 32 per wave-kstep); LDS was
// the largest pipe (2048 cyc/CU-iter vs 1320 MFMA). acc = 2x f32x16
// (32 VGPR, same as before). A-frag: row=lane&31, kchunk=lane>>5;
// C/D: col=lane&31, row=(reg&3)+8*(reg>>2)+4*(lane>>5) [m74/m101].
// Accumulation order changes (K=16 granularity) -> absmax ~0.0151 +-
// rounding, not bit-exact.
// =====================================================================
template<int EPI>
__global__ __launch_bounds__(256) void k_gemm(
    const u16* __restrict__ Ah, const u16* __restrict__ Al,
    const u16* __restrict__ Bt,
    u16* __restrict__ Ot, float* __restrict__ Orow,
    const u16* __restrict__ Xt)
{
    __shared__ __attribute__((aligned(16))) u16 AsH[2][64*64];
    __shared__ __attribute__((aligned(16))) u16 AsL[2][64*64];
    __shared__ __attribute__((aligned(16))) u16 Bs[2][128*64];
    const int tid = threadIdx.x;
    // XCD-aware bijective tile mapping (8 XCDs x 8x8 sub-grid)
    const int xc = blockIdx.x & 7, ii = blockIdx.x >> 3;
    const int bm = ((xc & 3)*8 + (ii & 7)) << 6;     // 32 row-tiles
    const int bn = ((xc >> 2)*8 + (ii >> 3)) << 7;   // 16 col-tiles
    const int w = tid >> 6, lane = tid & 63;
    const int wm = (w & 1) << 5;                     // 32 rows per wave
    const int wn = (w >> 1) << 6;                    // 64 cols per wave
    const int r31 = lane & 31;                       // frag row/col
    const int hk  = lane >> 5;                       // k-half
    const int key = lane & 7;                        // swizzle key (row&7)

    const int srow = tid >> 3, scol = (tid & 7) << 3;
    const long a0 = (long)(bm + srow)*2048 + scol;
    const long a1 = a0 + 32*2048;
    const long b0 = (long)(bn + srow)*2048 + scol;
    const long b1 = b0 + 32*2048;
    const long b2 = b0 + 64*2048;
    const long b3 = b0 + 96*2048;
    const int l0 = tid*8, l1 = tid*8 + 2048;

#define STAGE(B, K) do { \
        gll16(Ah + a0 + (K), &AsH[B][l0]); \
        gll16(Ah + a1 + (K), &AsH[B][l1]); \
        gll16(Al + a0 + (K), &AsL[B][l0]); \
        gll16(Al + a1 + (K), &AsL[B][l1]); \
        gll16(Bt + b0 + (K), &Bs[B][l0]); \
        gll16(Bt + b1 + (K), &Bs[B][l1]); \
        gll16(Bt + b2 + (K), &Bs[B][l0 + 4096]); \
        gll16(Bt + b3 + (K), &Bs[B][l1 + 4096]); \
    } while(0)

    f32x16 acc[2];
    #pragma unroll
    for (int i = 0; i < 2; i++)
        #pragma unroll
        for (int r = 0; r < 16; r++) acc[i][r] = 0.f;

    STAGE(0, 0);
    __syncthreads();
    int cur = 0;
    for (int k0 = 0; k0 < 2048; k0 += 64){
        if (k0 + 64 < 2048) STAGE(cur ^ 1, k0 + 64);
        const u16* ah = AsH[cur];
        const u16* al = AsL[cur];
        const u16* bs = Bs[cur];
        #pragma unroll
        for (int ks = 0; ks < 4; ks++){
            // physical u16 col of this lane's 8-elem K-chunk (chunk-swizzled)
            const int ca = (((2*ks + hk) ^ key)) << 3;
            s16x8 bv0 = *(const s16x8*)&bs[(wn +  0 + r31)*64 + ca];
            s16x8 bv1 = *(const s16x8*)&bs[(wn + 32 + r31)*64 + ca];
            s16x8 avh = *(const s16x8*)&ah[(wm + r31)*64 + ca];
            acc[0] = mfma32(avh, bv0, acc[0]);
            acc[1] = mfma32(avh, bv1, acc[1]);
            s16x8 avl = *(const s16x8*)&al[(wm + r31)*64 + ca];
            acc[0] = mfma32(avl, bv0, acc[0]);
            acc[1] = mfma32(avl, bv1, acc[1]);
        }
        __syncthreads();
        cur ^= 1;
    }
#undef STAGE

    #pragma unroll
    for (int ni = 0; ni < 2; ni++){
        int j  = bn + wn + ni*32 + r31;              // colG (C col = lane&31)
        int bb = j >> 7, cc = j & 127;
        #pragma unroll
        for (int g = 0; g < 4; g++){                 // reg group: rows i0..i0+3
            int i0 = bm + wm + 4*hk + 8*g;
            f32x4 v;
            #pragma unroll
            for (int q = 0; q < 4; q++) v[q] = acc[ni][4*g + q];
            if constexpr (EPI){
                u16x4 xh = *(const u16x4*)(Xt + (long)j*2048 + swz(j, i0));
                #pragma unroll
                for (int q = 0; q < 4; q++)
                    v[q] = 2.f*v[q] - h2f(xh[q]);
            }
            float* rp = Orow + ((long)bb*2048 + i0)*128 + cc;
            #pragma unroll
            for (int q = 0; q < 4; q++) rp[(long)q*128] = v[q];
            if constexpr (!EPI){
                u16x4 oh;
                #pragma unroll
                for (int q = 0; q < 4; q++) oh[q] = f2h(v[q]);
                *(u16x4*)(Ot + (long)j*2048 + swz(j, i0)) = oh;
            }
        }
    }
}

// =====================================================================
// Combine (round-6 proven, VERBATIM): out = sum_jc sum_d
// E[n,d]*(A_jc W[d]_jc) + bias. 256 thr, (256,2), d fully unrolled,
// triple-buffer W prefetch dist 2, zero-C first MFMA, VGPR 84.
// FUSE=1 (gate): fused zr = Zg@lw^T + candidate^T write.
// =====================================================================
template<int OFULL, int ACT, int FUSE>
__global__ __launch_bounds__(256, 2) void k_combine(
    const float* __restrict__ G1r, const float* __restrict__ G2r,
    const float* __restrict__ x, const float* __restrict__ second,
    const u16* __restrict__ W,
    const float* __restrict__ bias, const float* __restrict__ E,
    float* __restrict__ out, u16* __restrict__ XtT,
    const u16* __restrict__ lwt, const float* __restrict__ lb)
{
    constexpr int NO = OFULL/32;                 // o-frags per wave (4 gate, 2 upd)
    __shared__ u16 Ash[64*40], Asl[64*40];
    __shared__ float Et[640];
    __shared__ u16 Zh[FUSE ? 64*136 : 1];
    __shared__ u16 Zl[FUSE ? 64*136 : 1];
    const int tid = threadIdx.x, bid = blockIdx.x;
    const int b = bid >> 5, n0 = (bid & 31) << 6;
    const int w = tid >> 6, lane = tid & 63;
    const int wm = (w & 1)*32, wo = (w >> 1)*(OFULL/2);
    const int lr = lane & 15, lk = lane >> 4;

    for (int i = tid; i < 640; i += 256)
        Et[i] = E[(n0 + (i & 63))*10 + (i >> 6)];

    const f32x4 Z4 = {0.f, 0.f, 0.f, 0.f};
    f32x4 acc[2][NO];
    #pragma unroll
    for (int mi = 0; mi < 2; mi++)
        #pragma unroll
        for (int oi = 0; oi < NO; oi++) acc[mi][oi] = Z4;

    const long rowbase = (long)b*2048 + n0;
    const int laneoff = (wo + lr)*32 + lk*8;     // u16 offset within tile

    s16x8 pbh[3][NO];

    for (int jc = 0; jc < 12; jc++){
        // preload W tiles d=0,1 (independent of A; overlap staging+barrier)
        {
            const long t0 = (long)(jc*10 + 0)*OFULL*32;
            const long t1 = (long)(jc*10 + 1)*OFULL*32;
            #pragma unroll
            for (int oi = 0; oi < NO; oi++){
                pbh[0][oi] = *(const s16x8*)(W + t0 + laneoff + oi*16*32);
                pbh[1][oi] = *(const s16x8*)(W + t1 + laneoff + oi*16*32);
            }
        }
        __syncthreads();   // prior jc's A-frag reads are long done
        // ---- stage A (one 16B chunk per thread, f16 hi/lo) ----
        {
            const float* src; int stride;
            if (jc < 4){
                int col0 = jc*32;
                src = (col0 < 64) ? (x + rowbase*64 + col0)
                                  : (second + rowbase*64 + (col0 - 64));
                stride = 64;
            } else if (jc < 8){
                src = G1r + rowbase*128 + (jc-4)*32; stride = 128;
            } else {
                src = G2r + rowbase*128 + (jc-8)*32; stride = 128;
            }
            int row = tid >> 2, c8 = (tid & 3)*8;
            f32x4 s0 = *(const f32x4*)(src + (long)row*stride + c8);
            f32x4 s1 = *(const f32x4*)(src + (long)row*stride + c8 + 4);
            s16x8 vh, vl;
            #pragma unroll
            for (int t = 0; t < 4; t++){
                u16 h,l; split_h(s0[t], h, l); vh[t]=(short)h; vl[t]=(short)l;
            }
            #pragma unroll
            for (int t = 0; t < 4; t++){
                u16 h,l; split_h(s1[t], h, l); vh[4+t]=(short)h; vl[4+t]=(short)l;
            }
            *(s16x8*)&Ash[row*40 + c8] = vh;
            *(s16x8*)&Asl[row*40 + c8] = vl;
        }
        __syncthreads();

        s16x8 ah[2], al[2];
        #pragma unroll
        for (int mi = 0; mi < 2; mi++){
            ah[mi] = *(const s16x8*)&Ash[(wm + mi*16 + lr)*40 + lk*8];
            al[mi] = *(const s16x8*)&Asl[(wm + mi*16 + lr)*40 + lk*8];
        }

        #pragma unroll
        for (int d = 0; d < 10; d++){
            const int cur = d % 3;               // compile-time after unroll
            if (d < 8){                          // prefetch d+2 into slot (d+2)%3
                const int nx = (d + 2) % 3;
                const long t2 = (long)(jc*10 + d + 2)*OFULL*32;
                #pragma unroll
                for (int oi = 0; oi < NO; oi++)
                    pbh[nx][oi] = *(const s16x8*)(W + t2 + laneoff + oi*16*32);
            }
            f32x4 Cd[2][NO];
            #pragma unroll
            for (int mi = 0; mi < 2; mi++)
                #pragma unroll
                for (int oi = 0; oi < NO; oi++)
                    Cd[mi][oi] = mfma16(ah[mi], pbh[cur][oi], Z4);
            #pragma unroll
            for (int mi = 0; mi < 2; mi++)
                #pragma unroll
                for (int oi = 0; oi < NO; oi++)
                    Cd[mi][oi] = mfma16(al[mi], pbh[cur][oi], Cd[mi][oi]);
            #pragma unroll
            for (int mi = 0; mi < 2; mi++){
                f32x4 e4 = *(const f32x4*)&Et[d*64 + wm + mi*16 + lk*4];
                #pragma unroll
                for (int oi = 0; oi < NO; oi++) acc[mi][oi] += e4 * Cd[mi][oi];
            }
        }
    }

    if constexpr (!FUSE){
        #pragma unroll
        for (int mi = 0; mi < 2; mi++){
            #pragma unroll
            for (int oi = 0; oi < NO; oi++){
                int mrow = n0 + wm + mi*16 + lk*4;
                int o = wo + oi*16 + lr;
                #pragma unroll
                for (int r = 0; r < 4; r++){
                    float v = acc[mi][oi][r] + bias[(long)(mrow + r)*OFULL + o];
                    v = (ACT == 0) ? (1.f/(1.f + __expf(-v))) : tanhf(v);
                    out[((long)b*2048 + mrow + r)*OFULL + o] = v;
                }
            }
        }
    } else {
        // ---- fused: Zg = sigmoid(acc+bias) -> LDS limbs ----
        #pragma unroll
        for (int mi = 0; mi < 2; mi++){
            #pragma unroll
            for (int oi = 0; oi < NO; oi++){
                int lrow = wm + mi*16 + lk*4;
                int o = wo + oi*16 + lr;
                #pragma unroll
                for (int r = 0; r < 4; r++){
                    float v = acc[mi][oi][r] + bias[(long)(n0 + lrow + r)*OFULL + o];
                    v = 1.f/(1.f + __expf(-v));
                    u16 h, l; split_h(v, h, l);
                    Zh[(lrow + r)*136 + o] = h;
                    Zl[(lrow + r)*136 + o] = l;
                }
            }
        }
        __syncthreads();
        // ---- zr = Zg @ lw^T + lb ; wave w owns o-stripe w*16 ----
        f32x4 az[4];
        #pragma unroll
        for (int mi = 0; mi < 4; mi++) az[mi] = Z4;
        const int oz = w*16 + lr;
        #pragma unroll
        for (int ks = 0; ks < 4; ks++){
            s16x8 bw = *(const s16x8*)(lwt + oz*128 + ks*32 + lk*8);
            #pragma unroll
            for (int mi = 0; mi < 4; mi++){
                s16x8 zh = *(const s16x8*)&Zh[(mi*16 + lr)*136 + ks*32 + lk*8];
                az[mi] = mfma16(zh, bw, az[mi]);
            }
            #pragma unroll
            for (int mi = 0; mi < 4; mi++){
                s16x8 zl = *(const s16x8*)&Zl[(mi*16 + lr)*136 + ks*32 + lk*8];
                az[mi] = mfma16(zl, bw, az[mi]);
            }
        }
        const float lbv = lb[w*16 + lr];
        const int colG = b*128 + 64 + w*16 + lr;
        #pragma unroll
        for (int mi = 0; mi < 4; mi++){
            int mrow = n0 + mi*16 + lk*4;
            u16x4 tq;
            #pragma unroll
            for (int r = 0; r < 4; r++){
                float v = az[mi][r] + lbv;
                out[((long)b*2048 + mrow + r)*64 + w*16 + lr] = v;  // zr f32 rows
                tq[r] = f2h(v);
            }
            *(u16x4*)(XtT + (long)colG*2048 + swz(colG, mrow)) = tq; // candidate^T half
        }
    }
}

// =====================================================================
extern "C" void kernel_launch(void* const* d_in, const int* in_sizes, int n_in,
                              void* d_out, int out_size, void* d_ws, size_t ws_size,
                              hipStream_t stream)
{
    const float* x   = (const float*)d_in[0];
    const float* st  = (const float*)d_in[1];
    const float* E   = (const float*)d_in[2];
    const float* gwp = (const float*)d_in[3];
    const float* gbp = (const float*)d_in[4];
    const float* uwp = (const float*)d_in[5];
    const float* ubp = (const float*)d_in[6];
    const float* lw  = (const float*)d_in[7];
    const float* lb  = (const float*)d_in[8];
    float* out = (float*)d_out;
    char* ws = (char*)d_ws;

    const size_t MB8 = 8388608;
    u16*   Sh   = (u16*)(ws);                 // 8 MB
    u16*   Sl   = (u16*)(ws + 1*MB8);         // 8 MB
    u16*   Xt   = (u16*)(ws + 2*MB8);         // 8 MB (X^T gate -> candidate)
    u16*   G1t  = (u16*)(ws + 3*MB8);         // 8 MB
    float* G1row= (float*)(ws + 4*MB8);       // 16 MB
    float* G2row= (float*)(ws + 6*MB8);       // 16 MB
    float* zr   = (float*)(ws + 8*MB8);       // 8 MB
    char*  p    = ws + 9*MB8;
    u16* wg = (u16*)p;             p += 983040;
    u16* wu = (u16*)p;             p += 491520;
    float* bg = (float*)p;         p += 1048576;
    float* bu = (float*)p;         p += 524288;
    u16* lwt = (u16*)p;            p += 16384;

    // merged supports (2048 blocks) + prep (20832 blocks)
    k_prep<<<dim3(22880), dim3(256), 0, stream>>>(E, gwp, gbp, uwp, ubp, x, st, lw,
                                                  wg, wu, bg, bu, Xt, lwt, Sh, Sl);
    // gate diffusion
    k_gemm<0><<<dim3(512), dim3(256), 0, stream>>>(Sh, Sl, Xt, G1t, G1row,
                                                   (const u16*)nullptr);
    k_gemm<1><<<dim3(512), dim3(256), 0, stream>>>(Sh, Sl, G1t, (u16*)nullptr, G2row,
                                                   Xt);
    // gate combine -> zr (fused lin) + candidate^T zr-half into Xt
    k_combine<128,0,1><<<dim3(512), dim3(256), 0, stream>>>(G1row, G2row, x, st,
                                                            wg, bg, E, zr, Xt, lwt, lb);
    // update diffusion (Xt now = candidate^T)
    k_gemm<0><<<dim3(512), dim3(256), 0, stream>>>(Sh, Sl, Xt, G1t, G1row,
                                                   (const u16*)nullptr);
    k_gemm<1><<<dim3(512), dim3(256), 0, stream>>>(Sh, Sl, G1t, (u16*)nullptr, G2row,
                                                   Xt);
    // update combine -> out (tanh)
    k_combine<64,1,0><<<dim3(512), dim3(256), 0, stream>>>(G1row, G2row, x, zr,
                                                           wu, bu, E, out,
                                                           (u16*)nullptr,
                                                           (const u16*)nullptr,
                                                           (const float*)nullptr);
}

// Round 11
// 353.747 us; speedup vs baseline: 1.1644x; 1.0575x over previous
//
#include <hip/hip_runtime.h>

typedef unsigned short u16;
typedef short s16x8 __attribute__((ext_vector_type(8)));
typedef _Float16 h16x8 __attribute__((ext_vector_type(8)));
typedef float f32x4 __attribute__((ext_vector_type(4)));
typedef u16 u16x4 __attribute__((ext_vector_type(4)));

#define DEV static __device__ __forceinline__

// ---------- f16 limb helpers (RTNE via v_cvt_f16_f32) ----------
DEV u16 f2h(float x){ union { _Float16 h; u16 u; } v; v.h = (_Float16)x; return v.u; }
DEV float h2f(u16 u){ union { u16 u; _Float16 h; } v; v.u = u; return (float)v.h; }
DEV void split_h(float x, u16& h, u16& l){
    h = f2h(x);
    l = f2h(x - h2f(h));
}
DEV h16x8 H8(s16x8 v){ union { s16x8 s; h16x8 h; } u; u.s = v; return u.h; }
DEV f32x4 mfma16(s16x8 a, s16x8 b, f32x4 c){
    return __builtin_amdgcn_mfma_f32_16x16x32_f16(H8(a), H8(b), c, 0, 0, 0);
}

// ---------- t-layout chunk swizzle (bits 3-5 of m XOR row&7) ----------
DEV int swz(int r, int m){ return (m & ~0x38) | ((((m >> 3) ^ r) & 7) << 3); }

// global -> LDS direct (16B per lane)
DEV void gll16(const u16* g, u16* l){
    __builtin_amdgcn_global_load_lds((const __attribute__((address_space(1))) void*)g,
                                     (__attribute__((address_space(3))) void*)l, 16, 0, 0);
}

// =====================================================================
// K_prep (merged): blocks 0..2047 = supports softmax rows; rest = prep.
// =====================================================================
__global__ __launch_bounds__(256) void k_prep(const float* __restrict__ E,
    const float* __restrict__ gwp, const float* __restrict__ gbp,
    const float* __restrict__ uwp, const float* __restrict__ ubp,
    const float* __restrict__ x,   const float* __restrict__ state,
    const float* __restrict__ lw,
    u16* __restrict__ wg, u16* __restrict__ wu,
    float* __restrict__ bg, float* __restrict__ bu,
    u16* __restrict__ xt, u16* __restrict__ lwt,
    u16* __restrict__ Sh, u16* __restrict__ Sl)
{
    __shared__ float red[8];
    const int tid = threadIdx.x;
    if (blockIdx.x < 2048){
        const int n = blockIdx.x;
        const int w = tid >> 6, lane = tid & 63;
        float en[10];
        #pragma unroll
        for (int d = 0; d < 10; d++) en[d] = E[n*10 + d];
        float v[8];
        #pragma unroll
        for (int i = 0; i < 8; i++){
            int m = tid + i*256;
            const float* em = E + m*10;
            float s = 0.f;
            #pragma unroll
            for (int d = 0; d < 10; d++) s += en[d]*em[d];
            v[i] = fmaxf(s, 0.f);
        }
        float mx = v[0];
        #pragma unroll
        for (int i = 1; i < 8; i++) mx = fmaxf(mx, v[i]);
        #pragma unroll
        for (int off = 32; off > 0; off >>= 1) mx = fmaxf(mx, __shfl_xor(mx, off));
        if (lane == 0) red[w] = mx;
        __syncthreads();
        mx = fmaxf(fmaxf(red[0], red[1]), fmaxf(red[2], red[3]));
        __syncthreads();
        float sum = 0.f;
        #pragma unroll
        for (int i = 0; i < 8; i++){ v[i] = __expf(v[i] - mx); sum += v[i]; }
        #pragma unroll
        for (int off = 32; off > 0; off >>= 1) sum += __shfl_xor(sum, off);
        if (lane == 0) red[4 + w] = sum;
        __syncthreads();
        sum = red[4] + red[5] + red[6] + red[7];
        float inv = 1.f / sum;
        #pragma unroll
        for (int i = 0; i < 8; i++){
            float p = v[i] * inv;
            u16 h, l; split_h(p, h, l);
            int ms = swz(n, tid + i*256);
            Sh[n*2048 + ms] = h;
            Sl[n*2048 + ms] = l;
        }
        return;
    }
    long idx = (long)(blockIdx.x - 2048)*256 + tid;
    if (idx < 491520){                               // gate w -> [jc][d][128 o][32 k]
        int kk = (int)(idx & 31);
        int o  = (int)((idx >> 5) & 127);
        int r2 = (int)(idx >> 12);                   // 0..119
        int d = r2 % 10, jc = r2 / 10;
        int j = jc*32 + kk;                          // 0..383
        int k = j >> 7, i = j & 127;
        float v = gwp[(((d*3 + k)*128) + i)*128 + o];
        wg[idx] = f2h(v);
    } else if (idx < 737280){                        // upd w -> [jc][d][64 o][32 k]
        long t = idx - 491520;
        int kk = (int)(t & 31);
        int o  = (int)((t >> 5) & 63);
        int r2 = (int)(t >> 11);                     // 0..119
        int d = r2 % 10, jc = r2 / 10;
        int j = jc*32 + kk;
        int k = j >> 7, i = j & 127;
        float v = uwp[(((d*3 + k)*128) + i)*64 + o];
        wu[t] = f2h(v);
    } else if (idx < 999424){                        // bias_g [2048][128]
        long t = idx - 737280; int n = (int)(t >> 7), o = (int)(t & 127);
        float s = 0.f;
        #pragma unroll
        for (int d = 0; d < 10; d++) s += E[n*10+d]*gbp[d*128+o];
        bg[t] = s;
    } else if (idx < 1130496){                       // bias_u [2048][64]
        long t = idx - 999424; int n = (int)(t >> 6), o = (int)(t & 63);
        float s = 0.f;
        #pragma unroll
        for (int d = 0; d < 10; d++) s += E[n*10+d]*ubp[d*64+o];
        bu[t] = s;
    } else if (idx < 5324800){                       // X_gate^T pack (single f16, swz)
        long t = idx - 1130496;
        int colG = (int)(t >> 11), m = (int)(t & 2047);
        int b = colG >> 7, c = colG & 127;
        float v = (c < 64) ? x[((long)(b*2048)+m)*64 + c]
                           : state[((long)(b*2048)+m)*64 + c - 64];
        xt[(long)colG*2048 + swz(colG, m)] = f2h(v);
    } else if (idx < 5332992){                       // lin_w [64 o][128 k] -> f16
        long t = idx - 5324800;
        lwt[t] = f2h(lw[t]);
    }
}

// =====================================================================
// Diffusion GEMM (round-6 proven, VERBATIM — five alternates all null
// or regressed: staging-swizzle r7, A-in-regs r8, K-split r9, 32x32 r10).
// =====================================================================
template<int EPI>
__global__ __launch_bounds__(256) void k_gemm(
    const u16* __restrict__ Ah, const u16* __restrict__ Al,
    const u16* __restrict__ Bt,
    u16* __restrict__ Ot, float* __restrict__ Orow,
    const u16* __restrict__ Xt)
{
    __shared__ __attribute__((aligned(16))) u16 AsH[2][64*64];
    __shared__ __attribute__((aligned(16))) u16 AsL[2][64*64];
    __shared__ __attribute__((aligned(16))) u16 Bs[2][128*64];
    const int tid = threadIdx.x;
    // XCD-aware bijective tile mapping (8 XCDs x 8x8 sub-grid)
    const int xc = blockIdx.x & 7, ii = blockIdx.x >> 3;
    const int bm = ((xc & 3)*8 + (ii & 7)) << 6;     // 32 row-tiles
    const int bn = ((xc >> 2)*8 + (ii >> 3)) << 7;   // 16 col-tiles
    const int w = tid >> 6, lane = tid & 63;
    const int wm = (w & 1) << 5;                     // 32 rows per wave
    const int wn = (w >> 1) << 6;                    // 64 cols per wave
    const int lr = lane & 15, lk = lane >> 4;

    const int srow = tid >> 3, scol = (tid & 7) << 3;
    const long a0 = (long)(bm + srow)*2048 + scol;
    const long a1 = a0 + 32*2048;
    const long b0 = (long)(bn + srow)*2048 + scol;
    const long b1 = b0 + 32*2048;
    const long b2 = b0 + 64*2048;
    const long b3 = b0 + 96*2048;
    const int l0 = tid*8, l1 = tid*8 + 2048;

    const int c0 = (lk ^ (lr & 7)) << 3;
    const int c1 = c0 ^ 32;

#define STAGE(B, K) do { \
        gll16(Ah + a0 + (K), &AsH[B][l0]); \
        gll16(Ah + a1 + (K), &AsH[B][l1]); \
        gll16(Al + a0 + (K), &AsL[B][l0]); \
        gll16(Al + a1 + (K), &AsL[B][l1]); \
        gll16(Bt + b0 + (K), &Bs[B][l0]); \
        gll16(Bt + b1 + (K), &Bs[B][l1]); \
        gll16(Bt + b2 + (K), &Bs[B][l0 + 4096]); \
        gll16(Bt + b3 + (K), &Bs[B][l1 + 4096]); \
    } while(0)

    f32x4 acc[2][4];
    const f32x4 Z4 = {0.f, 0.f, 0.f, 0.f};
    #pragma unroll
    for (int i = 0; i < 2; i++)
        #pragma unroll
        for (int j = 0; j < 4; j++) acc[i][j] = Z4;

    STAGE(0, 0);
    __syncthreads();
    int cur = 0;
    for (int k0 = 0; k0 < 2048; k0 += 64){
        if (k0 + 64 < 2048) STAGE(cur ^ 1, k0 + 64);
        const u16* ah = AsH[cur];
        const u16* al = AsL[cur];
        const u16* bs = Bs[cur];
        #pragma unroll
        for (int s2 = 0; s2 < 2; s2++){
            const int cc = s2 ? c1 : c0;
            s16x8 bfv[4], af[2];
            #pragma unroll
            for (int ni = 0; ni < 4; ni++)
                bfv[ni] = *(const s16x8*)&bs[(wn + ni*16 + lr)*64 + cc];
            #pragma unroll
            for (int mi = 0; mi < 2; mi++)
                af[mi] = *(const s16x8*)&ah[(wm + mi*16 + lr)*64 + cc];
            #pragma unroll
            for (int mi = 0; mi < 2; mi++)
                #pragma unroll
                for (int ni = 0; ni < 4; ni++)
                    acc[mi][ni] = mfma16(af[mi], bfv[ni], acc[mi][ni]);
            #pragma unroll
            for (int mi = 0; mi < 2; mi++)
                af[mi] = *(const s16x8*)&al[(wm + mi*16 + lr)*64 + cc];
            #pragma unroll
            for (int mi = 0; mi < 2; mi++)
                #pragma unroll
                for (int ni = 0; ni < 4; ni++)
                    acc[mi][ni] = mfma16(af[mi], bfv[ni], acc[mi][ni]);
        }
        __syncthreads();
        cur ^= 1;
    }
#undef STAGE

    #pragma unroll
    for (int mi = 0; mi < 2; mi++){
        #pragma unroll
        for (int ni = 0; ni < 4; ni++){
            int i0 = bm + wm + mi*16 + lk*4;
            int j  = bn + wn + ni*16 + lr;
            f32x4 v = acc[mi][ni];
            if constexpr (EPI){
                u16x4 xh = *(const u16x4*)(Xt + (long)j*2048 + swz(j, i0));
                #pragma unroll
                for (int r = 0; r < 4; r++)
                    v[r] = 2.f*v[r] - h2f(xh[r]);
            }
            int bb = j >> 7, cc = j & 127;
            float* rp = Orow + ((long)bb*2048 + i0)*128 + cc;
            #pragma unroll
            for (int r = 0; r < 4; r++) rp[(long)r*128] = v[r];
            if constexpr (!EPI){
                u16x4 oh;
                #pragma unroll
                for (int r = 0; r < 4; r++) oh[r] = f2h(v[r]);
                *(u16x4*)(Ot + (long)j*2048 + swz(j, i0)) = oh;
            }
        }
    }
}

// =====================================================================
// Gate combine v2 (512 threads, 8 waves): each wave owns ONE 16-o
// stripe over all 4 row-frags (mi=4, NO=1). Occupancy 8->16 waves/CU
// (2 blocks/CU x 8 waves, VGPR ~100 < 128 cliff); A staged once/block;
// W read once/block (wave-pair duplication gone -> W L2 traffic /2).
// Per-output math & accumulation order identical to round-6 ->
// absmax canary 0.01513672. Fused zr + candidate^T epilogue retained
// (zr gemm split: wave w -> o-stripe (w&3)*16, row-half (w>>2)*32).
// =====================================================================
__global__ __launch_bounds__(512) void k_combineG(
    const float* __restrict__ G1r, const float* __restrict__ G2r,
    const float* __restrict__ x, const float* __restrict__ second,
    const u16* __restrict__ W,
    const float* __restrict__ bias, const float* __restrict__ E,
    float* __restrict__ out, u16* __restrict__ XtT,
    const u16* __restrict__ lwt, const float* __restrict__ lb)
{
    __shared__ u16 Ash[64*40], Asl[64*40];
    __shared__ float Et[640];
    __shared__ u16 Zh[64*136], Zl[64*136];
    const int tid = threadIdx.x, bid = blockIdx.x;
    const int b = bid >> 5, n0 = (bid & 31) << 6;
    const int w = tid >> 6, lane = tid & 63;
    const int wo = w << 4;                        // wave's 16-o stripe
    const int lr = lane & 15, lk = lane >> 4;

    for (int i = tid; i < 640; i += 512)
        Et[i] = E[(n0 + (i & 63))*10 + (i >> 6)];

    const f32x4 Z4 = {0.f, 0.f, 0.f, 0.f};
    f32x4 acc[4];
    #pragma unroll
    for (int mi = 0; mi < 4; mi++) acc[mi] = Z4;

    const long rowbase = (long)b*2048 + n0;
    const int laneoff = (wo + lr)*32 + lk*8;      // u16 offset within W tile

    s16x8 pbh[3];

    for (int jc = 0; jc < 12; jc++){
        // preload W tiles d=0,1
        {
            const long t0 = (long)(jc*10 + 0)*128*32;
            const long t1 = (long)(jc*10 + 1)*128*32;
            pbh[0] = *(const s16x8*)(W + t0 + laneoff);
            pbh[1] = *(const s16x8*)(W + t1 + laneoff);
        }
        __syncthreads();   // prior jc's A-frag reads done
        // ---- stage A (512 thr: one f32x4 per thread) ----
        {
            const float* src; int stride;
            if (jc < 4){
                int col0 = jc*32;
                src = (col0 < 64) ? (x + rowbase*64 + col0)
                                  : (second + rowbase*64 + (col0 - 64));
                stride = 64;
            } else if (jc < 8){
                src = G1r + rowbase*128 + (jc-4)*32; stride = 128;
            } else {
                src = G2r + rowbase*128 + (jc-8)*32; stride = 128;
            }
            int row = tid >> 3, c4 = (tid & 7)*4;
            f32x4 s0 = *(const f32x4*)(src + (long)row*stride + c4);
            u16x4 vh, vl;
            #pragma unroll
            for (int t = 0; t < 4; t++){
                u16 h,l; split_h(s0[t], h, l); vh[t]=h; vl[t]=l;
            }
            *(u16x4*)&Ash[row*40 + c4] = vh;
            *(u16x4*)&Asl[row*40 + c4] = vl;
        }
        __syncthreads();

        s16x8 ah[4], al[4];
        #pragma unroll
        for (int mi = 0; mi < 4; mi++){
            ah[mi] = *(const s16x8*)&Ash[(mi*16 + lr)*40 + lk*8];
            al[mi] = *(const s16x8*)&Asl[(mi*16 + lr)*40 + lk*8];
        }

        #pragma unroll
        for (int d = 0; d < 10; d++){
            const int cur = d % 3;
            if (d < 8){
                const int nx = (d + 2) % 3;
                const long t2 = (long)(jc*10 + d + 2)*128*32;
                pbh[nx] = *(const s16x8*)(W + t2 + laneoff);
            }
            f32x4 Cd[4];
            #pragma unroll
            for (int mi = 0; mi < 4; mi++)
                Cd[mi] = mfma16(ah[mi], pbh[cur], Z4);
            #pragma unroll
            for (int mi = 0; mi < 4; mi++)
                Cd[mi] = mfma16(al[mi], pbh[cur], Cd[mi]);
            #pragma unroll
            for (int mi = 0; mi < 4; mi++){
                f32x4 e4 = *(const f32x4*)&Et[d*64 + mi*16 + lk*4];
                acc[mi] += e4 * Cd[mi];
            }
        }
    }

    // ---- fused: Zg = sigmoid(acc+bias) -> LDS limbs ----
    #pragma unroll
    for (int mi = 0; mi < 4; mi++){
        int lrow = mi*16 + lk*4;
        int o = wo + lr;
        #pragma unroll
        for (int r = 0; r < 4; r++){
            float v = acc[mi][r] + bias[(long)(n0 + lrow + r)*128 + o];
            v = 1.f/(1.f + __expf(-v));
            u16 h, l; split_h(v, h, l);
            Zh[(lrow + r)*136 + o] = h;
            Zl[(lrow + r)*136 + o] = l;
        }
    }
    __syncthreads();
    // ---- zr = Zg @ lw^T + lb ; wave w: o-stripe (w&3)*16, rows (w>>2)*32 ----
    f32x4 az[2] = {Z4, Z4};
    const int ow = (w & 3) << 4;
    const int rh = (w >> 2) << 5;
    #pragma unroll
    for (int ks = 0; ks < 4; ks++){
        s16x8 bw = *(const s16x8*)(lwt + (ow + lr)*128 + ks*32 + lk*8);
        #pragma unroll
        for (int mi = 0; mi < 2; mi++){
            s16x8 zh = *(const s16x8*)&Zh[(rh + mi*16 + lr)*136 + ks*32 + lk*8];
            az[mi] = mfma16(zh, bw, az[mi]);
        }
        #pragma unroll
        for (int mi = 0; mi < 2; mi++){
            s16x8 zl = *(const s16x8*)&Zl[(rh + mi*16 + lr)*136 + ks*32 + lk*8];
            az[mi] = mfma16(zl, bw, az[mi]);
        }
    }
    const float lbv = lb[ow + lr];
    const int colG = b*128 + 64 + ow + lr;
    #pragma unroll
    for (int mi = 0; mi < 2; mi++){
        int mrow = n0 + rh + mi*16 + lk*4;
        u16x4 tq;
        #pragma unroll
        for (int r = 0; r < 4; r++){
            float v = az[mi][r] + lbv;
            out[((long)b*2048 + mrow + r)*64 + ow + lr] = v;   // zr f32 rows
            tq[r] = f2h(v);
        }
        *(u16x4*)(XtT + (long)colG*2048 + swz(colG, mrow)) = tq; // candidate^T half
    }
}

// =====================================================================
// Update combine (round-6 proven, VERBATIM, FUSE=0 path).
// =====================================================================
template<int OFULL, int ACT>
__global__ __launch_bounds__(256, 2) void k_combine(
    const float* __restrict__ G1r, const float* __restrict__ G2r,
    const float* __restrict__ x, const float* __restrict__ second,
    const u16* __restrict__ W,
    const float* __restrict__ bias, const float* __restrict__ E,
    float* __restrict__ out)
{
    constexpr int NO = OFULL/32;
    __shared__ u16 Ash[64*40], Asl[64*40];
    __shared__ float Et[640];
    const int tid = threadIdx.x, bid = blockIdx.x;
    const int b = bid >> 5, n0 = (bid & 31) << 6;
    const int w = tid >> 6, lane = tid & 63;
    const int wm = (w & 1)*32, wo = (w >> 1)*(OFULL/2);
    const int lr = lane & 15, lk = lane >> 4;

    for (int i = tid; i < 640; i += 256)
        Et[i] = E[(n0 + (i & 63))*10 + (i >> 6)];

    const f32x4 Z4 = {0.f, 0.f, 0.f, 0.f};
    f32x4 acc[2][NO];
    #pragma unroll
    for (int mi = 0; mi < 2; mi++)
        #pragma unroll
        for (int oi = 0; oi < NO; oi++) acc[mi][oi] = Z4;

    const long rowbase = (long)b*2048 + n0;
    const int laneoff = (wo + lr)*32 + lk*8;

    s16x8 pbh[3][NO];

    for (int jc = 0; jc < 12; jc++){
        {
            const long t0 = (long)(jc*10 + 0)*OFULL*32;
            const long t1 = (long)(jc*10 + 1)*OFULL*32;
            #pragma unroll
            for (int oi = 0; oi < NO; oi++){
                pbh[0][oi] = *(const s16x8*)(W + t0 + laneoff + oi*16*32);
                pbh[1][oi] = *(const s16x8*)(W + t1 + laneoff + oi*16*32);
            }
        }
        __syncthreads();
        {
            const float* src; int stride;
            if (jc < 4){
                int col0 = jc*32;
                src = (col0 < 64) ? (x + rowbase*64 + col0)
                                  : (second + rowbase*64 + (col0 - 64));
                stride = 64;
            } else if (jc < 8){
                src = G1r + rowbase*128 + (jc-4)*32; stride = 128;
            } else {
                src = G2r + rowbase*128 + (jc-8)*32; stride = 128;
            }
            int row = tid >> 2, c8 = (tid & 3)*8;
            f32x4 s0 = *(const f32x4*)(src + (long)row*stride + c8);
            f32x4 s1 = *(const f32x4*)(src + (long)row*stride + c8 + 4);
            s16x8 vh, vl;
            #pragma unroll
            for (int t = 0; t < 4; t++){
                u16 h,l; split_h(s0[t], h, l); vh[t]=(short)h; vl[t]=(short)l;
            }
            #pragma unroll
            for (int t = 0; t < 4; t++){
                u16 h,l; split_h(s1[t], h, l); vh[4+t]=(short)h; vl[4+t]=(short)l;
            }
            *(s16x8*)&Ash[row*40 + c8] = vh;
            *(s16x8*)&Asl[row*40 + c8] = vl;
        }
        __syncthreads();

        s16x8 ah[2], al[2];
        #pragma unroll
        for (int mi = 0; mi < 2; mi++){
            ah[mi] = *(const s16x8*)&Ash[(wm + mi*16 + lr)*40 + lk*8];
            al[mi] = *(const s16x8*)&Asl[(wm + mi*16 + lr)*40 + lk*8];
        }

        #pragma unroll
        for (int d = 0; d < 10; d++){
            const int cur = d % 3;
            if (d < 8){
                const int nx = (d + 2) % 3;
                const long t2 = (long)(jc*10 + d + 2)*OFULL*32;
                #pragma unroll
                for (int oi = 0; oi < NO; oi++)
                    pbh[nx][oi] = *(const s16x8*)(W + t2 + laneoff + oi*16*32);
            }
            f32x4 Cd[2][NO];
            #pragma unroll
            for (int mi = 0; mi < 2; mi++)
                #pragma unroll
                for (int oi = 0; oi < NO; oi++)
                    Cd[mi][oi] = mfma16(ah[mi], pbh[cur][oi], Z4);
            #pragma unroll
            for (int mi = 0; mi < 2; mi++)
                #pragma unroll
                for (int oi = 0; oi < NO; oi++)
                    Cd[mi][oi] = mfma16(al[mi], pbh[cur][oi], Cd[mi][oi]);
            #pragma unroll
            for (int mi = 0; mi < 2; mi++){
                f32x4 e4 = *(const f32x4*)&Et[d*64 + wm + mi*16 + lk*4];
                #pragma unroll
                for (int oi = 0; oi < NO; oi++) acc[mi][oi] += e4 * Cd[mi][oi];
            }
        }
    }

    #pragma unroll
    for (int mi = 0; mi < 2; mi++){
        #pragma unroll
        for (int oi = 0; oi < NO; oi++){
            int mrow = n0 + wm + mi*16 + lk*4;
            int o = wo + oi*16 + lr;
            #pragma unroll
            for (int r = 0; r < 4; r++){
                float v = acc[mi][oi][r] + bias[(long)(mrow + r)*OFULL + o];
                v = (ACT == 0) ? (1.f/(1.f + __expf(-v))) : tanhf(v);
                out[((long)b*2048 + mrow + r)*OFULL + o] = v;
            }
        }
    }
}

// =====================================================================
extern "C" void kernel_launch(void* const* d_in, const int* in_sizes, int n_in,
                              void* d_out, int out_size, void* d_ws, size_t ws_size,
                              hipStream_t stream)
{
    const float* x   = (const float*)d_in[0];
    const float* st  = (const float*)d_in[1];
    const float* E   = (const float*)d_in[2];
    const float* gwp = (const float*)d_in[3];
    const float* gbp = (const float*)d_in[4];
    const float* uwp = (const float*)d_in[5];
    const float* ubp = (const float*)d_in[6];
    const float* lw  = (const float*)d_in[7];
    const float* lb  = (const float*)d_in[8];
    float* out = (float*)d_out;
    char* ws = (char*)d_ws;

    const size_t MB8 = 8388608;
    u16*   Sh   = (u16*)(ws);                 // 8 MB
    u16*   Sl   = (u16*)(ws + 1*MB8);         // 8 MB
    u16*   Xt   = (u16*)(ws + 2*MB8);         // 8 MB (X^T gate -> candidate)
    u16*   G1t  = (u16*)(ws + 3*MB8);         // 8 MB
    float* G1row= (float*)(ws + 4*MB8);       // 16 MB
    float* G2row= (float*)(ws + 6*MB8);       // 16 MB
    float* zr   = (float*)(ws + 8*MB8);       // 8 MB
    char*  p    = ws + 9*MB8;
    u16* wg = (u16*)p;             p += 983040;
    u16* wu = (u16*)p;             p += 491520;
    float* bg = (float*)p;         p += 1048576;
    float* bu = (float*)p;         p += 524288;
    u16* lwt = (u16*)p;            p += 16384;

    // merged supports (2048 blocks) + prep (20832 blocks)
    k_prep<<<dim3(22880), dim3(256), 0, stream>>>(E, gwp, gbp, uwp, ubp, x, st, lw,
                                                  wg, wu, bg, bu, Xt, lwt, Sh, Sl);
    // gate diffusion
    k_gemm<0><<<dim3(512), dim3(256), 0, stream>>>(Sh, Sl, Xt, G1t, G1row,
                                                   (const u16*)nullptr);
    k_gemm<1><<<dim3(512), dim3(256), 0, stream>>>(Sh, Sl, G1t, (u16*)nullptr, G2row,
                                                   Xt);
    // gate combine (512-thr, 8-wave o-split) -> zr + candidate^T into Xt
    k_combineG<<<dim3(512), dim3(512), 0, stream>>>(G1row, G2row, x, st,
                                                    wg, bg, E, zr, Xt, lwt, lb);
    // update diffusion (Xt now = candidate^T)
    k_gemm<0><<<dim3(512), dim3(256), 0, stream>>>(Sh, Sl, Xt, G1t, G1row,
                                                   (const u16*)nullptr);
    k_gemm<1><<<dim3(512), dim3(256), 0, stream>>>(Sh, Sl, G1t, (u16*)nullptr, G2row,
                                                   Xt);
    // update combine -> out (tanh)
    k_combine<64,1><<<dim3(512), dim3(256), 0, stream>>>(G1row, G2row, x, zr,
                                                         wu, bu, E, out);
}